// Round 1
// baseline (1115.421 us; speedup 1.0000x reference)
//
#include <hip/hip_runtime.h>

typedef __bf16 bf16;
typedef __bf16 bf16x4 __attribute__((ext_vector_type(4)));
typedef __bf16 bf16x8 __attribute__((ext_vector_type(8)));
typedef float  f32x4  __attribute__((ext_vector_type(4)));

// Problem constants
#define NB    16384      // batch
#define NOBS  568
#define NH    256
#define NAG   19         // N_OTHER

// ws byte offsets (all 16B aligned)
#define OFF_WT_MU    0u          // [256][576] bf16
#define OFF_WT_VAR   294912u     // [256][576]
#define OFF_WT_SELF  589824u     // [256][64]
#define OFF_WT_OTHER 622592u     // [256][32]
#define OFF_WT_Q     638976u     // [256][256]
#define OFF_WT_K     770048u
#define OFF_WT_V1    901120u
#define OFF_WT_V2    1032192u
#define OFF_WT_A1    1163264u
#define OFF_WT_A2    1294336u
#define OFF_Z        1425408u    // [16384][256] bf16
#define OFF_SELF     9814016u
#define OFF_Q        18202624u
#define OFF_SV       26591232u   // bf16 (includes b_v)
#define OFF_H        34979840u
#define OFF_SCORES   43368448u   // [16384][19] f32

// ---------------------------------------------------------------------------
// Weight prep: fp32 W[k][n] -> bf16 Wt[n][kpad] (zero-padded K)
// ---------------------------------------------------------------------------
__global__ __launch_bounds__(256) void wprep(
    const float* __restrict__ Wmu, const float* __restrict__ Wvar,
    const float* __restrict__ Wself, const float* __restrict__ Wother,
    const float* __restrict__ Wq, const float* __restrict__ Wk,
    const float* __restrict__ Wv, const float* __restrict__ Wa, char* wsb)
{
  const float* src; bf16* dst; int K, Kp;
  switch (blockIdx.y) {
    case 0: src = Wmu;        dst = (bf16*)(wsb + OFF_WT_MU);    K = 568; Kp = 576; break;
    case 1: src = Wvar;       dst = (bf16*)(wsb + OFF_WT_VAR);   K = 568; Kp = 576; break;
    case 2: src = Wself;      dst = (bf16*)(wsb + OFF_WT_SELF);  K = 36;  Kp = 64;  break;
    case 3: src = Wother;     dst = (bf16*)(wsb + OFF_WT_OTHER); K = 28;  Kp = 32;  break;
    case 4: src = Wq;         dst = (bf16*)(wsb + OFF_WT_Q);     K = 256; Kp = 256; break;
    case 5: src = Wk;         dst = (bf16*)(wsb + OFF_WT_K);     K = 256; Kp = 256; break;
    case 6: src = Wv;         dst = (bf16*)(wsb + OFF_WT_V1);    K = 256; Kp = 256; break;
    case 7: src = Wv + 65536; dst = (bf16*)(wsb + OFF_WT_V2);    K = 256; Kp = 256; break;
    case 8: src = Wa;         dst = (bf16*)(wsb + OFF_WT_A1);    K = 256; Kp = 256; break;
    default: src = Wa + 65536; dst = (bf16*)(wsb + OFF_WT_A2);   K = 256; Kp = 256; break;
  }
  int total = 256 * Kp;
  for (int i = blockIdx.x * 256 + threadIdx.x; i < total; i += gridDim.x * 256) {
    int n = i / Kp, k = i - n * Kp;
    dst[i] = (k < K) ? (bf16)src[k * 256 + n] : (bf16)0.f;
  }
}

// ---------------------------------------------------------------------------
// Generic 64-row GEMM: wave w owns rows [w*16,w*16+16) x all 256 cols.
// EMODE: 0 = Z (dual Wt: mu & logvar -> z bf16), 1 = relu->bf16,
//        2 = +bias->bf16 (no relu), 3 = dual-A relu->f32 (final out)
// ---------------------------------------------------------------------------
template<int EMODE, bool AF32>
__global__ __launch_bounds__(256, 2) void gemm_k(
    const void* __restrict__ Aptr, const void* __restrict__ A2ptr,
    int lda, int K, int Klimit,
    const bf16* __restrict__ Wt, const bf16* __restrict__ Wt2,
    const float* __restrict__ bias, const float* __restrict__ bias2,
    const float* __restrict__ epsp, void* __restrict__ outp)
{
  constexpr bool DUALB = (EMODE == 0);
  constexpr bool DUALA = (EMODE == 3);
  __shared__ bf16 ldsA[64 * 72];
  __shared__ bf16 ldsB[256 * 72];
  __shared__ bf16 ldsB2[DUALB ? 256 * 72 : 8];

  const int tid = threadIdx.x;
  const int wave = tid >> 6;
  const int lane = tid & 63;
  const int quad = lane >> 4;
  const int m = lane & 15;
  const int rowbase = blockIdx.x * 64;

  f32x4 acc[16];
  f32x4 accB[DUALB ? 16 : 1];
  const f32x4 z4 = {0.f, 0.f, 0.f, 0.f};
#pragma unroll
  for (int ct = 0; ct < 16; ++ct) acc[ct] = z4;
  if constexpr (DUALB) {
#pragma unroll
    for (int ct = 0; ct < 16; ++ct) accB[ct] = z4;
  }

  const int npass = DUALA ? 2 : 1;
  for (int pass = 0; pass < npass; ++pass) {
    const void* Ap = (pass == 0) ? Aptr : A2ptr;
    const bf16* Wp = (pass == 0) ? Wt : Wt2;
    for (int kc = 0; kc < K; kc += 64) {
      __syncthreads();
      if constexpr (AF32) {
        const float* Af = (const float*)Ap;
        for (int p = tid; p < 1024; p += 256) {
          int r = p >> 4, fp = p & 15;
          int k = kc + fp * 4;
          const float* src = Af + (size_t)(rowbase + r) * lda + k;
          float v0, v1, v2, v3;
          if (k + 4 <= Klimit) {
            float4 v = *(const float4*)src;
            v0 = v.x; v1 = v.y; v2 = v.z; v3 = v.w;
          } else {
            v0 = (k + 0 < Klimit) ? src[0] : 0.f;
            v1 = (k + 1 < Klimit) ? src[1] : 0.f;
            v2 = (k + 2 < Klimit) ? src[2] : 0.f;
            v3 = (k + 3 < Klimit) ? src[3] : 0.f;
          }
          bf16x4 o = {(bf16)v0, (bf16)v1, (bf16)v2, (bf16)v3};
          *(bf16x4*)(ldsA + r * 72 + fp * 4) = o;
        }
      } else {
        const bf16* Ab = (const bf16*)Ap;
        for (int p = tid; p < 512; p += 256) {
          int r = p >> 3, fp = p & 7;
          *(bf16x8*)(ldsA + r * 72 + fp * 8) =
              *(const bf16x8*)(Ab + (size_t)(rowbase + r) * lda + kc + fp * 8);
        }
      }
      for (int p = tid; p < 2048; p += 256) {
        int n = p >> 3, fp = p & 7;
        *(bf16x8*)(ldsB + n * 72 + fp * 8) =
            *(const bf16x8*)(Wp + (size_t)n * K + kc + fp * 8);
      }
      if constexpr (DUALB) {
        for (int p = tid; p < 2048; p += 256) {
          int n = p >> 3, fp = p & 7;
          *(bf16x8*)(ldsB2 + n * 72 + fp * 8) =
              *(const bf16x8*)(Wt2 + (size_t)n * K + kc + fp * 8);
        }
      }
      __syncthreads();
#pragma unroll
      for (int s = 0; s < 2; ++s) {
        bf16x8 afrag = *(const bf16x8*)(ldsA + (wave * 16 + m) * 72 + s * 32 + quad * 8);
#pragma unroll
        for (int ct = 0; ct < 16; ++ct) {
          bf16x8 bfrag = *(const bf16x8*)(ldsB + (ct * 16 + m) * 72 + s * 32 + quad * 8);
          acc[ct] = __builtin_amdgcn_mfma_f32_16x16x32_bf16(afrag, bfrag, acc[ct], 0, 0, 0);
          if constexpr (DUALB) {
            bf16x8 b2 = *(const bf16x8*)(ldsB2 + (ct * 16 + m) * 72 + s * 32 + quad * 8);
            accB[ct] = __builtin_amdgcn_mfma_f32_16x16x32_bf16(afrag, b2, accB[ct], 0, 0, 0);
          }
        }
      }
    }
  }
#pragma unroll
  for (int ct = 0; ct < 16; ++ct) {
    const int col = ct * 16 + m;
    const float bv = bias[col];
#pragma unroll
    for (int r = 0; r < 4; ++r) {
      const size_t row = (size_t)rowbase + wave * 16 + quad * 4 + r;
      float v = acc[ct][r] + bv;
      if constexpr (EMODE == 0) {
        float lv = accB[ct][r] + bias2[col];
        float zz = epsp[row * 256 + col] * __expf(0.5f * lv) + v;
        ((bf16*)outp)[row * 256 + col] = (bf16)zz;
      } else if constexpr (EMODE == 1) {
        ((bf16*)outp)[row * 256 + col] = (bf16)(v > 0.f ? v : 0.f);
      } else if constexpr (EMODE == 2) {
        ((bf16*)outp)[row * 256 + col] = (bf16)v;
      } else {
        ((float*)outp)[row * 256 + col] = (v > 0.f ? v : 0.f);
      }
    }
  }
}

// ---------------------------------------------------------------------------
// Scores: per block 64 agent-rows (g = b*19+n). other_em -> k -> dot(q,k)/16
// ---------------------------------------------------------------------------
__global__ __launch_bounds__(256, 2) void k_scores(
    const float* __restrict__ x, const bf16* __restrict__ qb,
    const bf16* __restrict__ WtOther, const float* __restrict__ b_other,
    const bf16* __restrict__ WtK, const float* __restrict__ b_k,
    float* __restrict__ scores)
{
  __shared__ bf16 ldsA1[64 * 40];
  __shared__ bf16 ldsO[64 * 264];
  __shared__ bf16 ldsB[256 * 40];
  __shared__ float qlds[5 * 256];
  const int tid = threadIdx.x, wave = tid >> 6, lane = tid & 63;
  const int quad = lane >> 4, m = lane & 15;
  const int rowbase = blockIdx.x * 64;
  const int b0 = rowbase / 19;

  for (int i = tid; i < 5 * 256; i += 256) {
    int bb = b0 + (i >> 8);
    qlds[i] = (bb < NB) ? (float)qb[(size_t)bb * 256 + (i & 255)] : 0.f;
  }
  for (int i = tid; i < 64 * 32; i += 256) {
    int r = i >> 5, k = i & 31;
    int g = rowbase + r;
    int bb = g / 19;
    int n = g - bb * 19;
    float v = (k < 28) ? x[(size_t)bb * NOBS + 36 + n * 28 + k] : 0.f;
    ldsA1[r * 40 + k] = (bf16)v;
  }
  for (int p = tid; p < 1024; p += 256) {
    int n = p >> 2, fp = p & 3;
    *(bf16x8*)(ldsB + n * 40 + fp * 8) = *(const bf16x8*)(WtOther + n * 32 + fp * 8);
  }
  __syncthreads();

  const f32x4 z4 = {0.f, 0.f, 0.f, 0.f};
  f32x4 acc[16];
#pragma unroll
  for (int ct = 0; ct < 16; ++ct) acc[ct] = z4;
  {
    bf16x8 a = *(const bf16x8*)(ldsA1 + (wave * 16 + m) * 40 + quad * 8);
#pragma unroll
    for (int ct = 0; ct < 16; ++ct) {
      bf16x8 bb = *(const bf16x8*)(ldsB + (ct * 16 + m) * 40 + quad * 8);
      acc[ct] = __builtin_amdgcn_mfma_f32_16x16x32_bf16(a, bb, acc[ct], 0, 0, 0);
    }
  }
#pragma unroll
  for (int ct = 0; ct < 16; ++ct) {
    int col = ct * 16 + m;
    float bv = b_other[col];
#pragma unroll
    for (int r = 0; r < 4; ++r) {
      float v = acc[ct][r] + bv;
      v = v > 0.f ? v : 0.f;
      ldsO[(wave * 16 + quad * 4 + r) * 264 + col] = (bf16)v;
    }
  }

  f32x4 acc2[16];
#pragma unroll
  for (int ct = 0; ct < 16; ++ct) acc2[ct] = z4;
  for (int kc = 0; kc < 256; kc += 32) {
    __syncthreads();
    for (int p = tid; p < 1024; p += 256) {
      int n = p >> 2, fp = p & 3;
      *(bf16x8*)(ldsB + n * 40 + fp * 8) =
          *(const bf16x8*)(WtK + (size_t)n * 256 + kc + fp * 8);
    }
    __syncthreads();
    bf16x8 a = *(const bf16x8*)(ldsO + (wave * 16 + m) * 264 + kc + quad * 8);
#pragma unroll
    for (int ct = 0; ct < 16; ++ct) {
      bf16x8 bb = *(const bf16x8*)(ldsB + (ct * 16 + m) * 40 + quad * 8);
      acc2[ct] = __builtin_amdgcn_mfma_f32_16x16x32_bf16(a, bb, acc2[ct], 0, 0, 0);
    }
  }

  int bloc[4];
#pragma unroll
  for (int r = 0; r < 4; ++r) bloc[r] = (rowbase + wave * 16 + quad * 4 + r) / 19 - b0;
  float part[4] = {0.f, 0.f, 0.f, 0.f};
#pragma unroll
  for (int ct = 0; ct < 16; ++ct) {
    int col = ct * 16 + m;
    float bv = b_k[col];
#pragma unroll
    for (int r = 0; r < 4; ++r) {
      float kv = acc2[ct][r] + bv;
      kv = kv > 0.f ? kv : 0.f;
      part[r] += kv * qlds[bloc[r] * 256 + col];
    }
  }
#pragma unroll
  for (int r = 0; r < 4; ++r) {
    float p = part[r];
    p += __shfl_xor(p, 1, 64);
    p += __shfl_xor(p, 2, 64);
    p += __shfl_xor(p, 4, 64);
    p += __shfl_xor(p, 8, 64);
    if (m == 0) scores[(size_t)rowbase + wave * 16 + quad * 4 + r] = p * 0.0625f;
  }
}

// ---------------------------------------------------------------------------
// Softmax + v (other-half; self-half preadded via sv) + h + att output.
// Block: 4 batches -> 76 agent rows (5 row-tiles of 16, wave0 takes 2 tiles)
// ---------------------------------------------------------------------------
__global__ __launch_bounds__(256, 2) void k_att_h(
    const float* __restrict__ x, const float* __restrict__ scores,
    const bf16* __restrict__ svb,
    const bf16* __restrict__ WtOther, const float* __restrict__ b_other,
    const bf16* __restrict__ WtV1,
    float* __restrict__ att_out, bf16* __restrict__ hb)
{
  __shared__ bf16 ldsA1[80 * 40];
  __shared__ bf16 ldsO[80 * 264];   // other_em, later reused for att*v
  __shared__ bf16 ldsB[256 * 40];
  __shared__ float svl[4 * 256];
  __shared__ float attl[4 * 19];
  const int tid = threadIdx.x, wave = tid >> 6, lane = tid & 63;
  const int quad = lane >> 4, m = lane & 15;
  const int b0 = blockIdx.x * 4;

  if (tid < 4) {
    const int bb = b0 + tid;
    const float* sp = scores + (size_t)bb * 19;
    float mx = -1e30f;
    for (int j = 0; j < 19; ++j) mx = fmaxf(mx, sp[j]);
    float sum = 0.f;
    for (int j = 0; j < 19; ++j) {
      float e = __expf(sp[j] - mx);
      attl[tid * 19 + j] = e;
      sum += e;
    }
    float inv = 1.f / sum;
    for (int j = 0; j < 19; ++j) {
      float a = attl[tid * 19 + j] * inv;
      attl[tid * 19 + j] = a;
      att_out[(size_t)bb * 19 + j] = a;
    }
  }
  for (int i = tid; i < 1024; i += 256) svl[i] = (float)svb[(size_t)b0 * 256 + i];
  for (int i = tid; i < 80 * 32; i += 256) {
    int r = i >> 5, k = i & 31;
    float v = 0.f;
    if (r < 76 && k < 28) {
      int bb = b0 + r / 19;
      int n = r % 19;
      v = x[(size_t)bb * NOBS + 36 + n * 28 + k];
    }
    ldsA1[r * 40 + k] = (bf16)v;
  }
  for (int p = tid; p < 1024; p += 256) {
    int n = p >> 2, fp = p & 3;
    *(bf16x8*)(ldsB + n * 40 + fp * 8) = *(const bf16x8*)(WtOther + n * 32 + fp * 8);
  }
  __syncthreads();

  const f32x4 z4 = {0.f, 0.f, 0.f, 0.f};
  for (int rt = wave; rt < 5; rt += 4) {
    f32x4 acc[16];
#pragma unroll
    for (int ct = 0; ct < 16; ++ct) acc[ct] = z4;
    bf16x8 a = *(const bf16x8*)(ldsA1 + (rt * 16 + m) * 40 + quad * 8);
#pragma unroll
    for (int ct = 0; ct < 16; ++ct) {
      bf16x8 bb = *(const bf16x8*)(ldsB + (ct * 16 + m) * 40 + quad * 8);
      acc[ct] = __builtin_amdgcn_mfma_f32_16x16x32_bf16(a, bb, acc[ct], 0, 0, 0);
    }
#pragma unroll
    for (int ct = 0; ct < 16; ++ct) {
      int col = ct * 16 + m;
      float bv = b_other[col];
#pragma unroll
      for (int r = 0; r < 4; ++r) {
        float v = acc[ct][r] + bv;
        v = v > 0.f ? v : 0.f;
        ldsO[(rt * 16 + quad * 4 + r) * 264 + col] = (bf16)v;
      }
    }
  }

  const int ntiles = (wave == 0) ? 2 : 1;
  f32x4 acc2[2][16];
#pragma unroll
  for (int t = 0; t < 2; ++t)
#pragma unroll
    for (int ct = 0; ct < 16; ++ct) acc2[t][ct] = z4;

  for (int kc = 0; kc < 256; kc += 32) {
    __syncthreads();
    for (int p = tid; p < 1024; p += 256) {
      int n = p >> 2, fp = p & 3;
      *(bf16x8*)(ldsB + n * 40 + fp * 8) =
          *(const bf16x8*)(WtV1 + (size_t)n * 256 + kc + fp * 8);
    }
    __syncthreads();
    for (int t = 0; t < ntiles; ++t) {
      const int rt = (t == 0) ? wave : 4;
      bf16x8 a = *(const bf16x8*)(ldsO + (rt * 16 + m) * 264 + kc + quad * 8);
#pragma unroll
      for (int ct = 0; ct < 16; ++ct) {
        bf16x8 bb = *(const bf16x8*)(ldsB + (ct * 16 + m) * 40 + quad * 8);
        acc2[t][ct] = __builtin_amdgcn_mfma_f32_16x16x32_bf16(a, bb, acc2[t][ct], 0, 0, 0);
      }
    }
  }
  __syncthreads();
  for (int t = 0; t < ntiles; ++t) {
    const int rt = (t == 0) ? wave : 4;
#pragma unroll
    for (int ct = 0; ct < 16; ++ct) {
      int col = ct * 16 + m;
#pragma unroll
      for (int r = 0; r < 4; ++r) {
        int rowl = rt * 16 + quad * 4 + r;
        if (rowl < 76) {
          int bl = rowl / 19;
          int nn = rowl - bl * 19;
          float v = acc2[t][ct][r] + svl[bl * 256 + col];
          v = v > 0.f ? v : 0.f;
          v *= attl[bl * 19 + nn];
          ldsO[rowl * 264 + col] = (bf16)v;
        }
      }
    }
  }
  __syncthreads();
  for (int i = tid; i < 1024; i += 256) {
    int bl = i >> 8, col = i & 255;
    float s = 0.f;
    const bf16* vp = ldsO + (bl * 19) * 264 + col;
#pragma unroll
    for (int j = 0; j < 19; ++j) s += (float)vp[j * 264];
    hb[(size_t)(b0 + bl) * 256 + col] = (bf16)s;
  }
}

// ---------------------------------------------------------------------------
extern "C" void kernel_launch(void* const* d_in, const int* in_sizes, int n_in,
                              void* d_out, int out_size, void* d_ws, size_t ws_size,
                              hipStream_t stream) {
  (void)in_sizes; (void)n_in; (void)out_size; (void)ws_size;
  const float* x      = (const float*)d_in[0];
  const float* eps    = (const float*)d_in[1];
  const float* W_mu   = (const float*)d_in[2];
  const float* b_mu   = (const float*)d_in[3];
  const float* W_var  = (const float*)d_in[4];
  const float* b_var  = (const float*)d_in[5];
  const float* W_self = (const float*)d_in[6];
  const float* b_self = (const float*)d_in[7];
  const float* W_other= (const float*)d_in[8];
  const float* b_other= (const float*)d_in[9];
  const float* W_q    = (const float*)d_in[10];
  const float* b_q    = (const float*)d_in[11];
  const float* W_k    = (const float*)d_in[12];
  const float* b_k    = (const float*)d_in[13];
  const float* W_v    = (const float*)d_in[14];
  const float* b_v    = (const float*)d_in[15];
  const float* W_a    = (const float*)d_in[16];
  const float* b_a    = (const float*)d_in[17];

  char* wsb = (char*)d_ws;
  bf16* WtMu    = (bf16*)(wsb + OFF_WT_MU);
  bf16* WtVar   = (bf16*)(wsb + OFF_WT_VAR);
  bf16* WtSelf  = (bf16*)(wsb + OFF_WT_SELF);
  bf16* WtOther = (bf16*)(wsb + OFF_WT_OTHER);
  bf16* WtQ     = (bf16*)(wsb + OFF_WT_Q);
  bf16* WtK     = (bf16*)(wsb + OFF_WT_K);
  bf16* WtV1    = (bf16*)(wsb + OFF_WT_V1);
  bf16* WtV2    = (bf16*)(wsb + OFF_WT_V2);
  bf16* WtA1    = (bf16*)(wsb + OFF_WT_A1);
  bf16* WtA2    = (bf16*)(wsb + OFF_WT_A2);
  bf16* zbuf    = (bf16*)(wsb + OFF_Z);
  bf16* selfbuf = (bf16*)(wsb + OFF_SELF);
  bf16* qbuf    = (bf16*)(wsb + OFF_Q);
  bf16* svbuf   = (bf16*)(wsb + OFF_SV);
  bf16* hbuf    = (bf16*)(wsb + OFF_H);
  float* scores = (float*)(wsb + OFF_SCORES);

  float* out = (float*)d_out;
  float* att_out = out + (size_t)NB * 256;

  dim3 blk(256);
  wprep<<<dim3(160, 10), blk, 0, stream>>>(W_mu, W_var, W_self, W_other, W_q, W_k, W_v, W_a, wsb);
  // z = eps*exp(0.5*logvar)+mu  (fused mu/var GEMM, K=576)
  gemm_k<0, true><<<NB / 64, blk, 0, stream>>>(x, nullptr, 568, 576, 568,
                                               WtMu, WtVar, b_mu, b_var, eps, zbuf);
  // self_em = relu(x[:, :36] @ W_self + b_self)  (K=64, zero-padded weights)
  gemm_k<1, true><<<NB / 64, blk, 0, stream>>>(x, nullptr, 568, 64, 568,
                                               WtSelf, nullptr, b_self, nullptr, nullptr, selfbuf);
  // q = relu(z @ W_q + b_q)
  gemm_k<1, false><<<NB / 64, blk, 0, stream>>>(zbuf, nullptr, 256, 256, 256,
                                                WtQ, nullptr, b_q, nullptr, nullptr, qbuf);
  // sv = self_em @ W_v[256:] + b_v   (no relu)
  gemm_k<2, false><<<NB / 64, blk, 0, stream>>>(selfbuf, nullptr, 256, 256, 256,
                                                WtV2, nullptr, b_v, nullptr, nullptr, svbuf);
  // scores
  k_scores<<<(NB * NAG) / 64, blk, 0, stream>>>(x, qbuf, WtOther, b_other, WtK, b_k, scores);
  // softmax + v + h (+ att output)
  k_att_h<<<NB / 4, blk, 0, stream>>>(x, scores, svbuf, WtOther, b_other, WtV1, att_out, hbuf);
  // out = relu([h; self_em] @ W_a + b_a)
  gemm_k<3, false><<<NB / 64, blk, 0, stream>>>(hbuf, selfbuf, 256, 256, 256,
                                                WtA1, WtA2, b_a, nullptr, nullptr, out);
}

// Round 2
// 657.161 us; speedup vs baseline: 1.6973x; 1.6973x over previous
//
#include <hip/hip_runtime.h>

typedef __bf16 bf16;
typedef __bf16 bf16x4 __attribute__((ext_vector_type(4)));
typedef __bf16 bf16x8 __attribute__((ext_vector_type(8)));
typedef float  f32x4  __attribute__((ext_vector_type(4)));

// Problem constants
#define NB    16384      // batch
#define NOBS  568
#define NH    256
#define NAG   19         // N_OTHER

// ws byte offsets (all 16B aligned)
#define OFF_WT_MU    0u          // [256][576] bf16
#define OFF_WT_VAR   294912u     // [256][576]
#define OFF_WT_SELF  589824u     // [256][64]
#define OFF_WT_OTHER 622592u     // [256][32]
#define OFF_WT_Q     638976u     // [256][256]
#define OFF_WT_K     770048u
#define OFF_WT_V1    901120u
#define OFF_WT_V2    1032192u
#define OFF_WT_A1    1163264u
#define OFF_WT_A2    1294336u
#define OFF_Z        1425408u    // [16384][256] bf16
#define OFF_SELF     9814016u
#define OFF_Q        18202624u
#define OFF_SV       26591232u   // bf16 (includes b_v)
#define OFF_H        34979840u
#define OFF_SCORES   43368448u   // [16384][19] f32

// ---------------------------------------------------------------------------
// Weight prep: fp32 W[k][n] -> bf16 Wt[n][kpad] (zero-padded K)
// ---------------------------------------------------------------------------
__global__ __launch_bounds__(256) void wprep(
    const float* __restrict__ Wmu, const float* __restrict__ Wvar,
    const float* __restrict__ Wself, const float* __restrict__ Wother,
    const float* __restrict__ Wq, const float* __restrict__ Wk,
    const float* __restrict__ Wv, const float* __restrict__ Wa, char* wsb)
{
  const float* src; bf16* dst; int K, Kp;
  switch (blockIdx.y) {
    case 0: src = Wmu;        dst = (bf16*)(wsb + OFF_WT_MU);    K = 568; Kp = 576; break;
    case 1: src = Wvar;       dst = (bf16*)(wsb + OFF_WT_VAR);   K = 568; Kp = 576; break;
    case 2: src = Wself;      dst = (bf16*)(wsb + OFF_WT_SELF);  K = 36;  Kp = 64;  break;
    case 3: src = Wother;     dst = (bf16*)(wsb + OFF_WT_OTHER); K = 28;  Kp = 32;  break;
    case 4: src = Wq;         dst = (bf16*)(wsb + OFF_WT_Q);     K = 256; Kp = 256; break;
    case 5: src = Wk;         dst = (bf16*)(wsb + OFF_WT_K);     K = 256; Kp = 256; break;
    case 6: src = Wv;         dst = (bf16*)(wsb + OFF_WT_V1);    K = 256; Kp = 256; break;
    case 7: src = Wv + 65536; dst = (bf16*)(wsb + OFF_WT_V2);    K = 256; Kp = 256; break;
    case 8: src = Wa;         dst = (bf16*)(wsb + OFF_WT_A1);    K = 256; Kp = 256; break;
    default: src = Wa + 65536; dst = (bf16*)(wsb + OFF_WT_A2);   K = 256; Kp = 256; break;
  }
  int total = 256 * Kp;
  for (int i = blockIdx.x * 256 + threadIdx.x; i < total; i += gridDim.x * 256) {
    int n = i / Kp, k = i - n * Kp;
    dst[i] = (k < K) ? (bf16)src[k * 256 + n] : (bf16)0.f;
  }
}

// ---------------------------------------------------------------------------
// Generic 64-row GEMM: wave w owns rows [w*16,w*16+16) x all 256 cols.
// EMODE: 0 = Z (dual Wt: mu & logvar -> z bf16), 1 = relu->bf16,
//        2 = +bias->bf16 (no relu), 3 = dual-A relu->f32 (final out)
// ---------------------------------------------------------------------------
template<int EMODE, bool AF32>
__global__ __launch_bounds__(256, 2) void gemm_k(
    const void* __restrict__ Aptr, const void* __restrict__ A2ptr,
    int lda, int K, int Klimit,
    const bf16* __restrict__ Wt, const bf16* __restrict__ Wt2,
    const float* __restrict__ bias, const float* __restrict__ bias2,
    const float* __restrict__ epsp, void* __restrict__ outp)
{
  constexpr bool DUALB = (EMODE == 0);
  constexpr bool DUALA = (EMODE == 3);
  __shared__ bf16 ldsA[64 * 72];
  __shared__ bf16 ldsB[256 * 72];
  __shared__ bf16 ldsB2[DUALB ? 256 * 72 : 8];

  const int tid = threadIdx.x;
  const int wave = tid >> 6;
  const int lane = tid & 63;
  const int quad = lane >> 4;
  const int m = lane & 15;
  const int rowbase = blockIdx.x * 64;

  f32x4 acc[16];
  f32x4 accB[DUALB ? 16 : 1];
  const f32x4 z4 = {0.f, 0.f, 0.f, 0.f};
#pragma unroll
  for (int ct = 0; ct < 16; ++ct) acc[ct] = z4;
  if constexpr (DUALB) {
#pragma unroll
    for (int ct = 0; ct < 16; ++ct) accB[ct] = z4;
  }

  const int npass = DUALA ? 2 : 1;
  for (int pass = 0; pass < npass; ++pass) {
    const void* Ap = (pass == 0) ? Aptr : A2ptr;
    const bf16* Wp = (pass == 0) ? Wt : Wt2;
    for (int kc = 0; kc < K; kc += 64) {
      __syncthreads();
      if constexpr (AF32) {
        const float* Af = (const float*)Ap;
        for (int p = tid; p < 1024; p += 256) {
          int r = p >> 4, fp = p & 15;
          int k = kc + fp * 4;
          const float* src = Af + (size_t)(rowbase + r) * lda + k;
          float v0, v1, v2, v3;
          if (k + 4 <= Klimit) {
            float4 v = *(const float4*)src;
            v0 = v.x; v1 = v.y; v2 = v.z; v3 = v.w;
          } else {
            v0 = (k + 0 < Klimit) ? src[0] : 0.f;
            v1 = (k + 1 < Klimit) ? src[1] : 0.f;
            v2 = (k + 2 < Klimit) ? src[2] : 0.f;
            v3 = (k + 3 < Klimit) ? src[3] : 0.f;
          }
          bf16x4 o = {(bf16)v0, (bf16)v1, (bf16)v2, (bf16)v3};
          *(bf16x4*)(ldsA + r * 72 + fp * 4) = o;
        }
      } else {
        const bf16* Ab = (const bf16*)Ap;
        for (int p = tid; p < 512; p += 256) {
          int r = p >> 3, fp = p & 7;
          *(bf16x8*)(ldsA + r * 72 + fp * 8) =
              *(const bf16x8*)(Ab + (size_t)(rowbase + r) * lda + kc + fp * 8);
        }
      }
      for (int p = tid; p < 2048; p += 256) {
        int n = p >> 3, fp = p & 7;
        *(bf16x8*)(ldsB + n * 72 + fp * 8) =
            *(const bf16x8*)(Wp + (size_t)n * K + kc + fp * 8);
      }
      if constexpr (DUALB) {
        for (int p = tid; p < 2048; p += 256) {
          int n = p >> 3, fp = p & 7;
          *(bf16x8*)(ldsB2 + n * 72 + fp * 8) =
              *(const bf16x8*)(Wt2 + (size_t)n * K + kc + fp * 8);
        }
      }
      __syncthreads();
#pragma unroll
      for (int s = 0; s < 2; ++s) {
        bf16x8 afrag = *(const bf16x8*)(ldsA + (wave * 16 + m) * 72 + s * 32 + quad * 8);
#pragma unroll
        for (int ct = 0; ct < 16; ++ct) {
          bf16x8 bfrag = *(const bf16x8*)(ldsB + (ct * 16 + m) * 72 + s * 32 + quad * 8);
          acc[ct] = __builtin_amdgcn_mfma_f32_16x16x32_bf16(afrag, bfrag, acc[ct], 0, 0, 0);
          if constexpr (DUALB) {
            bf16x8 b2 = *(const bf16x8*)(ldsB2 + (ct * 16 + m) * 72 + s * 32 + quad * 8);
            accB[ct] = __builtin_amdgcn_mfma_f32_16x16x32_bf16(afrag, b2, accB[ct], 0, 0, 0);
          }
        }
      }
    }
  }
#pragma unroll
  for (int ct = 0; ct < 16; ++ct) {
    const int col = ct * 16 + m;
    const float bv = bias[col];
#pragma unroll
    for (int r = 0; r < 4; ++r) {
      const size_t row = (size_t)rowbase + wave * 16 + quad * 4 + r;
      float v = acc[ct][r] + bv;
      if constexpr (EMODE == 0) {
        float lv = accB[ct][r] + bias2[col];
        float zz = epsp[row * 256 + col] * __expf(0.5f * lv) + v;
        ((bf16*)outp)[row * 256 + col] = (bf16)zz;
      } else if constexpr (EMODE == 1) {
        ((bf16*)outp)[row * 256 + col] = (bf16)(v > 0.f ? v : 0.f);
      } else if constexpr (EMODE == 2) {
        ((bf16*)outp)[row * 256 + col] = (bf16)v;
      } else {
        ((float*)outp)[row * 256 + col] = (v > 0.f ? v : 0.f);
      }
    }
  }
}

// ---------------------------------------------------------------------------
// Scores: per block 64 agent-rows (g = b*19+n). other_em -> k -> dot(q,k)/16
// ---------------------------------------------------------------------------
__global__ __launch_bounds__(256, 2) void k_scores(
    const float* __restrict__ x, const bf16* __restrict__ qb,
    const bf16* __restrict__ WtOther, const float* __restrict__ b_other,
    const bf16* __restrict__ WtK, const float* __restrict__ b_k,
    float* __restrict__ scores)
{
  __shared__ bf16 ldsA1[64 * 40];
  __shared__ bf16 ldsO[64 * 264];
  __shared__ bf16 ldsB[256 * 40];
  __shared__ float qlds[5 * 256];
  const int tid = threadIdx.x, wave = tid >> 6, lane = tid & 63;
  const int quad = lane >> 4, m = lane & 15;
  const int rowbase = blockIdx.x * 64;
  const int b0 = rowbase / 19;

  for (int i = tid; i < 5 * 256; i += 256) {
    int bb = b0 + (i >> 8);
    qlds[i] = (bb < NB) ? (float)qb[(size_t)bb * 256 + (i & 255)] : 0.f;
  }
  for (int i = tid; i < 64 * 32; i += 256) {
    int r = i >> 5, k = i & 31;
    int g = rowbase + r;
    int bb = g / 19;
    int n = g - bb * 19;
    float v = (k < 28) ? x[(size_t)bb * NOBS + 36 + n * 28 + k] : 0.f;
    ldsA1[r * 40 + k] = (bf16)v;
  }
  for (int p = tid; p < 1024; p += 256) {
    int n = p >> 2, fp = p & 3;
    *(bf16x8*)(ldsB + n * 40 + fp * 8) = *(const bf16x8*)(WtOther + n * 32 + fp * 8);
  }
  __syncthreads();

  const f32x4 z4 = {0.f, 0.f, 0.f, 0.f};
  f32x4 acc[16];
#pragma unroll
  for (int ct = 0; ct < 16; ++ct) acc[ct] = z4;
  {
    bf16x8 a = *(const bf16x8*)(ldsA1 + (wave * 16 + m) * 40 + quad * 8);
#pragma unroll
    for (int ct = 0; ct < 16; ++ct) {
      bf16x8 bb = *(const bf16x8*)(ldsB + (ct * 16 + m) * 40 + quad * 8);
      acc[ct] = __builtin_amdgcn_mfma_f32_16x16x32_bf16(a, bb, acc[ct], 0, 0, 0);
    }
  }
#pragma unroll
  for (int ct = 0; ct < 16; ++ct) {
    int col = ct * 16 + m;
    float bv = b_other[col];
#pragma unroll
    for (int r = 0; r < 4; ++r) {
      float v = acc[ct][r] + bv;
      v = v > 0.f ? v : 0.f;
      ldsO[(wave * 16 + quad * 4 + r) * 264 + col] = (bf16)v;
    }
  }

  f32x4 acc2[16];
#pragma unroll
  for (int ct = 0; ct < 16; ++ct) acc2[ct] = z4;
  for (int kc = 0; kc < 256; kc += 32) {
    __syncthreads();
    for (int p = tid; p < 1024; p += 256) {
      int n = p >> 2, fp = p & 3;
      *(bf16x8*)(ldsB + n * 40 + fp * 8) =
          *(const bf16x8*)(WtK + (size_t)n * 256 + kc + fp * 8);
    }
    __syncthreads();
    bf16x8 a = *(const bf16x8*)(ldsO + (wave * 16 + m) * 264 + kc + quad * 8);
#pragma unroll
    for (int ct = 0; ct < 16; ++ct) {
      bf16x8 bb = *(const bf16x8*)(ldsB + (ct * 16 + m) * 40 + quad * 8);
      acc2[ct] = __builtin_amdgcn_mfma_f32_16x16x32_bf16(a, bb, acc2[ct], 0, 0, 0);
    }
  }

  int bloc[4];
#pragma unroll
  for (int r = 0; r < 4; ++r) bloc[r] = (rowbase + wave * 16 + quad * 4 + r) / 19 - b0;
  float part[4] = {0.f, 0.f, 0.f, 0.f};
#pragma unroll
  for (int ct = 0; ct < 16; ++ct) {
    int col = ct * 16 + m;
    float bv = b_k[col];
#pragma unroll
    for (int r = 0; r < 4; ++r) {
      float kv = acc2[ct][r] + bv;
      kv = kv > 0.f ? kv : 0.f;
      part[r] += kv * qlds[bloc[r] * 256 + col];
    }
  }
#pragma unroll
  for (int r = 0; r < 4; ++r) {
    float p = part[r];
    p += __shfl_xor(p, 1, 64);
    p += __shfl_xor(p, 2, 64);
    p += __shfl_xor(p, 4, 64);
    p += __shfl_xor(p, 8, 64);
    if (m == 0) scores[(size_t)rowbase + wave * 16 + quad * 4 + r] = p * 0.0625f;
  }
}

// ---------------------------------------------------------------------------
// Softmax + v (other-half; self-half preadded via sv) + h + att output.
// Block: 4 batches -> 76 agent rows (5 row-tiles of 16; wave w does tiles
// {w, w+4} with the second valid only for wave 0 -- COMPILE-TIME unrolled so
// acc2 indexing is static and stays in VGPRs (round-1 scratch-spill fix).
// ---------------------------------------------------------------------------
__global__ __launch_bounds__(256, 2) void k_att_h(
    const float* __restrict__ x, const float* __restrict__ scores,
    const bf16* __restrict__ svb,
    const bf16* __restrict__ WtOther, const float* __restrict__ b_other,
    const bf16* __restrict__ WtV1,
    float* __restrict__ att_out, bf16* __restrict__ hb)
{
  __shared__ bf16 ldsA1[80 * 40];
  __shared__ bf16 ldsO[80 * 264];   // other_em, later reused for att*v
  __shared__ bf16 ldsB[256 * 40];
  __shared__ float svl[4 * 256];
  __shared__ float attl[4 * 19];
  const int tid = threadIdx.x, wave = tid >> 6, lane = tid & 63;
  const int quad = lane >> 4, m = lane & 15;
  const int b0 = blockIdx.x * 4;

  if (tid < 4) {
    const int bb = b0 + tid;
    const float* sp = scores + (size_t)bb * 19;
    float mx = -1e30f;
    for (int j = 0; j < 19; ++j) mx = fmaxf(mx, sp[j]);
    float sum = 0.f;
    for (int j = 0; j < 19; ++j) {
      float e = __expf(sp[j] - mx);
      attl[tid * 19 + j] = e;
      sum += e;
    }
    float inv = 1.f / sum;
    for (int j = 0; j < 19; ++j) {
      float a = attl[tid * 19 + j] * inv;
      attl[tid * 19 + j] = a;
      att_out[(size_t)bb * 19 + j] = a;
    }
  }
  for (int i = tid; i < 1024; i += 256) svl[i] = (float)svb[(size_t)b0 * 256 + i];
  for (int i = tid; i < 80 * 32; i += 256) {
    int r = i >> 5, k = i & 31;
    float v = 0.f;
    if (r < 76 && k < 28) {
      int bb = b0 + r / 19;
      int n = r % 19;
      v = x[(size_t)bb * NOBS + 36 + n * 28 + k];
    }
    ldsA1[r * 40 + k] = (bf16)v;
  }
  for (int p = tid; p < 1024; p += 256) {
    int n = p >> 2, fp = p & 3;
    *(bf16x8*)(ldsB + n * 40 + fp * 8) = *(const bf16x8*)(WtOther + n * 32 + fp * 8);
  }
  __syncthreads();

  const f32x4 z4 = {0.f, 0.f, 0.f, 0.f};
#pragma unroll
  for (int t = 0; t < 2; ++t) {
    const int rt = wave + 4 * t;
    if (rt < 5) {
      f32x4 acc[16];
#pragma unroll
      for (int ct = 0; ct < 16; ++ct) acc[ct] = z4;
      bf16x8 a = *(const bf16x8*)(ldsA1 + (rt * 16 + m) * 40 + quad * 8);
#pragma unroll
      for (int ct = 0; ct < 16; ++ct) {
        bf16x8 bb = *(const bf16x8*)(ldsB + (ct * 16 + m) * 40 + quad * 8);
        acc[ct] = __builtin_amdgcn_mfma_f32_16x16x32_bf16(a, bb, acc[ct], 0, 0, 0);
      }
#pragma unroll
      for (int ct = 0; ct < 16; ++ct) {
        int col = ct * 16 + m;
        float bv = b_other[col];
#pragma unroll
        for (int r = 0; r < 4; ++r) {
          float v = acc[ct][r] + bv;
          v = v > 0.f ? v : 0.f;
          ldsO[(rt * 16 + quad * 4 + r) * 264 + col] = (bf16)v;
        }
      }
    }
  }

  f32x4 acc2[2][16];
#pragma unroll
  for (int t = 0; t < 2; ++t)
#pragma unroll
    for (int ct = 0; ct < 16; ++ct) acc2[t][ct] = z4;

  for (int kc = 0; kc < 256; kc += 32) {
    __syncthreads();
    for (int p = tid; p < 1024; p += 256) {
      int n = p >> 2, fp = p & 3;
      *(bf16x8*)(ldsB + n * 40 + fp * 8) =
          *(const bf16x8*)(WtV1 + (size_t)n * 256 + kc + fp * 8);
    }
    __syncthreads();
#pragma unroll
    for (int t = 0; t < 2; ++t) {
      const int rt = wave + 4 * t;
      if (rt < 5) {
        bf16x8 a = *(const bf16x8*)(ldsO + (rt * 16 + m) * 264 + kc + quad * 8);
#pragma unroll
        for (int ct = 0; ct < 16; ++ct) {
          bf16x8 bb = *(const bf16x8*)(ldsB + (ct * 16 + m) * 40 + quad * 8);
          acc2[t][ct] = __builtin_amdgcn_mfma_f32_16x16x32_bf16(a, bb, acc2[t][ct], 0, 0, 0);
        }
      }
    }
  }
  __syncthreads();
#pragma unroll
  for (int t = 0; t < 2; ++t) {
    const int rt = wave + 4 * t;
    if (rt < 5) {
#pragma unroll
      for (int ct = 0; ct < 16; ++ct) {
        int col = ct * 16 + m;
#pragma unroll
        for (int r = 0; r < 4; ++r) {
          int rowl = rt * 16 + quad * 4 + r;
          if (rowl < 76) {
            int bl = rowl / 19;
            int nn = rowl - bl * 19;
            float v = acc2[t][ct][r] + svl[bl * 256 + col];
            v = v > 0.f ? v : 0.f;
            v *= attl[bl * 19 + nn];
            ldsO[rowl * 264 + col] = (bf16)v;
          }
        }
      }
    }
  }
  __syncthreads();
  for (int i = tid; i < 1024; i += 256) {
    int bl = i >> 8, col = i & 255;
    float s = 0.f;
    const bf16* vp = ldsO + (bl * 19) * 264 + col;
#pragma unroll
    for (int j = 0; j < 19; ++j) s += (float)vp[j * 264];
    hb[(size_t)(b0 + bl) * 256 + col] = (bf16)s;
  }
}

// ---------------------------------------------------------------------------
extern "C" void kernel_launch(void* const* d_in, const int* in_sizes, int n_in,
                              void* d_out, int out_size, void* d_ws, size_t ws_size,
                              hipStream_t stream) {
  (void)in_sizes; (void)n_in; (void)out_size; (void)ws_size;
  const float* x      = (const float*)d_in[0];
  const float* eps    = (const float*)d_in[1];
  const float* W_mu   = (const float*)d_in[2];
  const float* b_mu   = (const float*)d_in[3];
  const float* W_var  = (const float*)d_in[4];
  const float* b_var  = (const float*)d_in[5];
  const float* W_self = (const float*)d_in[6];
  const float* b_self = (const float*)d_in[7];
  const float* W_other= (const float*)d_in[8];
  const float* b_other= (const float*)d_in[9];
  const float* W_q    = (const float*)d_in[10];
  const float* b_q    = (const float*)d_in[11];
  const float* W_k    = (const float*)d_in[12];
  const float* b_k    = (const float*)d_in[13];
  const float* W_v    = (const float*)d_in[14];
  const float* b_v    = (const float*)d_in[15];
  const float* W_a    = (const float*)d_in[16];
  const float* b_a    = (const float*)d_in[17];

  char* wsb = (char*)d_ws;
  bf16* WtMu    = (bf16*)(wsb + OFF_WT_MU);
  bf16* WtVar   = (bf16*)(wsb + OFF_WT_VAR);
  bf16* WtSelf  = (bf16*)(wsb + OFF_WT_SELF);
  bf16* WtOther = (bf16*)(wsb + OFF_WT_OTHER);
  bf16* WtQ     = (bf16*)(wsb + OFF_WT_Q);
  bf16* WtK     = (bf16*)(wsb + OFF_WT_K);
  bf16* WtV1    = (bf16*)(wsb + OFF_WT_V1);
  bf16* WtV2    = (bf16*)(wsb + OFF_WT_V2);
  bf16* WtA1    = (bf16*)(wsb + OFF_WT_A1);
  bf16* WtA2    = (bf16*)(wsb + OFF_WT_A2);
  bf16* zbuf    = (bf16*)(wsb + OFF_Z);
  bf16* selfbuf = (bf16*)(wsb + OFF_SELF);
  bf16* qbuf    = (bf16*)(wsb + OFF_Q);
  bf16* svbuf   = (bf16*)(wsb + OFF_SV);
  bf16* hbuf    = (bf16*)(wsb + OFF_H);
  float* scores = (float*)(wsb + OFF_SCORES);

  float* out = (float*)d_out;
  float* att_out = out + (size_t)NB * 256;

  dim3 blk(256);
  wprep<<<dim3(160, 10), blk, 0, stream>>>(W_mu, W_var, W_self, W_other, W_q, W_k, W_v, W_a, wsb);
  // z = eps*exp(0.5*logvar)+mu  (fused mu/var GEMM, K=576)
  gemm_k<0, true><<<NB / 64, blk, 0, stream>>>(x, nullptr, 568, 576, 568,
                                               WtMu, WtVar, b_mu, b_var, eps, zbuf);
  // self_em = relu(x[:, :36] @ W_self + b_self)  (K=64, zero-padded weights)
  gemm_k<1, true><<<NB / 64, blk, 0, stream>>>(x, nullptr, 568, 64, 568,
                                               WtSelf, nullptr, b_self, nullptr, nullptr, selfbuf);
  // q = relu(z @ W_q + b_q)
  gemm_k<1, false><<<NB / 64, blk, 0, stream>>>(zbuf, nullptr, 256, 256, 256,
                                                WtQ, nullptr, b_q, nullptr, nullptr, qbuf);
  // sv = self_em @ W_v[256:] + b_v   (no relu)
  gemm_k<2, false><<<NB / 64, blk, 0, stream>>>(selfbuf, nullptr, 256, 256, 256,
                                                WtV2, nullptr, b_v, nullptr, nullptr, svbuf);
  // scores
  k_scores<<<(NB * NAG) / 64, blk, 0, stream>>>(x, qbuf, WtOther, b_other, WtK, b_k, scores);
  // softmax + v + h (+ att output)
  k_att_h<<<NB / 4, blk, 0, stream>>>(x, scores, svbuf, WtOther, b_other, WtV1, att_out, hbuf);
  // out = relu([h; self_em] @ W_a + b_a)
  gemm_k<3, false><<<NB / 64, blk, 0, stream>>>(hbuf, selfbuf, 256, 256, 256,
                                                WtA1, WtA2, b_a, nullptr, nullptr, out);
}

// Round 3
// 526.634 us; speedup vs baseline: 2.1180x; 1.2479x over previous
//
#include <hip/hip_runtime.h>

typedef __bf16 bf16;
typedef __bf16 bf16x4 __attribute__((ext_vector_type(4)));
typedef __bf16 bf16x8 __attribute__((ext_vector_type(8)));
typedef float  f32x4  __attribute__((ext_vector_type(4)));

// Problem constants
#define NB    16384      // batch
#define NOBS  568
#define NH    256
#define NAG   19         // N_OTHER

// ws byte offsets (all 16B aligned)
#define OFF_WT_MU    0u          // [256][576] bf16
#define OFF_WT_VAR   294912u     // [256][576]
#define OFF_WT_SELF  589824u     // [256][64]
#define OFF_WT_OTHER 622592u     // [256][32]
#define OFF_WT_Q     638976u     // [256][256]
#define OFF_WT_K     770048u
#define OFF_WT_V1    901120u
#define OFF_WT_V2    1032192u
#define OFF_WT_A1    1163264u
#define OFF_WT_A2    1294336u
#define OFF_Z        1425408u    // [16384][256] bf16
#define OFF_SELF     9814016u
#define OFF_Q        18202624u
#define OFF_SV       26591232u   // bf16 (includes b_v)
#define OFF_H        34979840u

static __device__ __forceinline__ unsigned short bfbits(float v) {
  bf16 b = (bf16)v;
  union { bf16 b; unsigned short u; } cvt; cvt.b = b; return cvt.u;
}

// ---------------------------------------------------------------------------
// Weight prep: fp32 W[k][n] -> bf16 Wt[n][kpad] (zero-padded K)
// ---------------------------------------------------------------------------
__global__ __launch_bounds__(256) void wprep(
    const float* __restrict__ Wmu, const float* __restrict__ Wvar,
    const float* __restrict__ Wself, const float* __restrict__ Wother,
    const float* __restrict__ Wq, const float* __restrict__ Wk,
    const float* __restrict__ Wv, const float* __restrict__ Wa, char* wsb)
{
  const float* src; bf16* dst; int K, Kp;
  switch (blockIdx.y) {
    case 0: src = Wmu;        dst = (bf16*)(wsb + OFF_WT_MU);    K = 568; Kp = 576; break;
    case 1: src = Wvar;       dst = (bf16*)(wsb + OFF_WT_VAR);   K = 568; Kp = 576; break;
    case 2: src = Wself;      dst = (bf16*)(wsb + OFF_WT_SELF);  K = 36;  Kp = 64;  break;
    case 3: src = Wother;     dst = (bf16*)(wsb + OFF_WT_OTHER); K = 28;  Kp = 32;  break;
    case 4: src = Wq;         dst = (bf16*)(wsb + OFF_WT_Q);     K = 256; Kp = 256; break;
    case 5: src = Wk;         dst = (bf16*)(wsb + OFF_WT_K);     K = 256; Kp = 256; break;
    case 6: src = Wv;         dst = (bf16*)(wsb + OFF_WT_V1);    K = 256; Kp = 256; break;
    case 7: src = Wv + 65536; dst = (bf16*)(wsb + OFF_WT_V2);    K = 256; Kp = 256; break;
    case 8: src = Wa;         dst = (bf16*)(wsb + OFF_WT_A1);    K = 256; Kp = 256; break;
    default: src = Wa + 65536; dst = (bf16*)(wsb + OFF_WT_A2);   K = 256; Kp = 256; break;
  }
  int total = 256 * Kp;
  for (int i = blockIdx.x * 256 + threadIdx.x; i < total; i += gridDim.x * 256) {
    int n = i / Kp, k = i - n * Kp;
    dst[i] = (k < K) ? (bf16)src[k * 256 + n] : (bf16)0.f;
  }
}

// ---------------------------------------------------------------------------
// Generic 64-row GEMM: wave w owns rows [w*16,w*16+16) x all 256 cols.
// EMODE: 0 = Z (dual Wt: mu & logvar -> z bf16), 1 = relu->bf16,
//        2 = +bias->bf16 (no relu), 3 = dual-A relu->f32 (final out)
// ---------------------------------------------------------------------------
template<int EMODE, bool AF32>
__global__ __launch_bounds__(256, 2) void gemm_k(
    const void* __restrict__ Aptr, const void* __restrict__ A2ptr,
    int lda, int K, int Klimit,
    const bf16* __restrict__ Wt, const bf16* __restrict__ Wt2,
    const float* __restrict__ bias, const float* __restrict__ bias2,
    const float* __restrict__ epsp, void* __restrict__ outp)
{
  constexpr bool DUALB = (EMODE == 0);
  constexpr bool DUALA = (EMODE == 3);
  __shared__ bf16 ldsA[64 * 72];
  __shared__ bf16 ldsB[256 * 72];
  __shared__ bf16 ldsB2[DUALB ? 256 * 72 : 8];

  const int tid = threadIdx.x;
  const int wave = tid >> 6;
  const int lane = tid & 63;
  const int quad = lane >> 4;
  const int m = lane & 15;
  const int rowbase = blockIdx.x * 64;

  f32x4 acc[16];
  f32x4 accB[DUALB ? 16 : 1];
  const f32x4 z4 = {0.f, 0.f, 0.f, 0.f};
#pragma unroll
  for (int ct = 0; ct < 16; ++ct) acc[ct] = z4;
  if constexpr (DUALB) {
#pragma unroll
    for (int ct = 0; ct < 16; ++ct) accB[ct] = z4;
  }

  const int npass = DUALA ? 2 : 1;
  for (int pass = 0; pass < npass; ++pass) {
    const void* Ap = (pass == 0) ? Aptr : A2ptr;
    const bf16* Wp = (pass == 0) ? Wt : Wt2;
    for (int kc = 0; kc < K; kc += 64) {
      __syncthreads();
      if constexpr (AF32) {
        const float* Af = (const float*)Ap;
        for (int p = tid; p < 1024; p += 256) {
          int r = p >> 4, fp = p & 15;
          int k = kc + fp * 4;
          const float* src = Af + (size_t)(rowbase + r) * lda + k;
          float v0, v1, v2, v3;
          if (k + 4 <= Klimit) {
            float4 v = *(const float4*)src;
            v0 = v.x; v1 = v.y; v2 = v.z; v3 = v.w;
          } else {
            v0 = (k + 0 < Klimit) ? src[0] : 0.f;
            v1 = (k + 1 < Klimit) ? src[1] : 0.f;
            v2 = (k + 2 < Klimit) ? src[2] : 0.f;
            v3 = (k + 3 < Klimit) ? src[3] : 0.f;
          }
          bf16x4 o = {(bf16)v0, (bf16)v1, (bf16)v2, (bf16)v3};
          *(bf16x4*)(ldsA + r * 72 + fp * 4) = o;
        }
      } else {
        const bf16* Ab = (const bf16*)Ap;
        for (int p = tid; p < 512; p += 256) {
          int r = p >> 3, fp = p & 7;
          *(bf16x8*)(ldsA + r * 72 + fp * 8) =
              *(const bf16x8*)(Ab + (size_t)(rowbase + r) * lda + kc + fp * 8);
        }
      }
      for (int p = tid; p < 2048; p += 256) {
        int n = p >> 3, fp = p & 7;
        *(bf16x8*)(ldsB + n * 72 + fp * 8) =
            *(const bf16x8*)(Wp + (size_t)n * K + kc + fp * 8);
      }
      if constexpr (DUALB) {
        for (int p = tid; p < 2048; p += 256) {
          int n = p >> 3, fp = p & 7;
          *(bf16x8*)(ldsB2 + n * 72 + fp * 8) =
              *(const bf16x8*)(Wt2 + (size_t)n * K + kc + fp * 8);
        }
      }
      __syncthreads();
#pragma unroll
      for (int s = 0; s < 2; ++s) {
        bf16x8 afrag = *(const bf16x8*)(ldsA + (wave * 16 + m) * 72 + s * 32 + quad * 8);
#pragma unroll
        for (int ct = 0; ct < 16; ++ct) {
          bf16x8 bfrag = *(const bf16x8*)(ldsB + (ct * 16 + m) * 72 + s * 32 + quad * 8);
          acc[ct] = __builtin_amdgcn_mfma_f32_16x16x32_bf16(afrag, bfrag, acc[ct], 0, 0, 0);
          if constexpr (DUALB) {
            bf16x8 b2 = *(const bf16x8*)(ldsB2 + (ct * 16 + m) * 72 + s * 32 + quad * 8);
            accB[ct] = __builtin_amdgcn_mfma_f32_16x16x32_bf16(afrag, b2, accB[ct], 0, 0, 0);
          }
        }
      }
    }
  }
#pragma unroll
  for (int ct = 0; ct < 16; ++ct) {
    const int col = ct * 16 + m;
    const float bv = bias[col];
#pragma unroll
    for (int r = 0; r < 4; ++r) {
      const size_t row = (size_t)rowbase + wave * 16 + quad * 4 + r;
      float v = acc[ct][r] + bv;
      if constexpr (EMODE == 0) {
        float lv = accB[ct][r] + bias2[col];
        float zz = epsp[row * 256 + col] * __expf(0.5f * lv) + v;
        ((bf16*)outp)[row * 256 + col] = (bf16)zz;
      } else if constexpr (EMODE == 1) {
        ((bf16*)outp)[row * 256 + col] = (bf16)(v > 0.f ? v : 0.f);
      } else if constexpr (EMODE == 2) {
        ((bf16*)outp)[row * 256 + col] = (bf16)v;
      } else {
        ((float*)outp)[row * 256 + col] = (v > 0.f ? v : 0.f);
      }
    }
  }
}

// ---------------------------------------------------------------------------
// Fused attention: other_em -> k -> scores -> softmax -> v -> h, one kernel.
// Block = 4 batches = 76 agent rows (padded 80 = 5 row-tiles of 16).
// Wave w owns the 64-col strip [64w, 64w+64) (4 col-tiles) x ALL 5 row-tiles:
// per kc-chunk a wave reads 4 B-frags ONCE into regs + 5 A-frags -> 20 MFMA
// (4x better MFMA:ds_read ratio than the round-2 row-split).
// ---------------------------------------------------------------------------
__global__ __launch_bounds__(256, 2) void k_fused(
    const float* __restrict__ x, const bf16* __restrict__ qb,
    const bf16* __restrict__ svb,
    const bf16* __restrict__ WtOther, const float* __restrict__ b_other,
    const bf16* __restrict__ WtK, const float* __restrict__ b_k,
    const bf16* __restrict__ WtV1,
    float* __restrict__ att_out, bf16* __restrict__ hb)
{
  __shared__ bf16 ldsO[80 * 264];     // other_em (stride 264, +8 pad)
  __shared__ bf16 Bbuf[256 * 40];     // staged weight chunk [n][kc 32 +8 pad]
  __shared__ bf16 ldsA1[80 * 40];     // agents_info tile
  __shared__ float qh[1024];          // q (phases<=2), then h partials
  __shared__ float svl[1024];         // sv (self-half of v, incl. b_v)
  __shared__ float spart[4 * 96];     // per-wave score partials
  __shared__ float attl[96];          // att weights per row

  const int tid = threadIdx.x, wave = tid >> 6, lane = tid & 63;
  const int quad = lane >> 4, m = lane & 15;
  const int b0 = blockIdx.x * 4;

  // ---- phase 0: stage q, sv, agents_info, WtOther
  for (int i = tid; i < 1024; i += 256) {
    qh[i]  = (float)qb[(size_t)b0 * 256 + i];
    svl[i] = (float)svb[(size_t)b0 * 256 + i];
  }
  for (int i = tid; i < 80 * 16; i += 256) {
    int r = i >> 4, kk = (i & 15) * 2;
    float v0 = 0.f, v1 = 0.f;
    if (r < 76) {
      int bb = b0 + r / 19, n = r % 19;
      const float* base = x + (size_t)bb * NOBS + 36 + n * 28;
      if (kk < 28) v0 = base[kk];
      if (kk + 1 < 28) v1 = base[kk + 1];
    }
    unsigned u0 = bfbits(v0), u1 = bfbits(v1);
    *(unsigned*)(ldsA1 + r * 40 + kk) = u0 | (u1 << 16);
  }
  for (int p = tid; p < 1024; p += 256) {
    int n = p >> 2, f = p & 3;
    *(bf16x8*)(Bbuf + n * 40 + f * 8) = *(const bf16x8*)(WtOther + n * 32 + f * 8);
  }
  __syncthreads();

  const f32x4 z4 = {0.f, 0.f, 0.f, 0.f};
  f32x4 acc[5][4];

  // ---- phase 1: other_em = relu(A1 @ WtOther^T + b_other), K=32 (one step)
  {
    bf16x8 bfr[4];
#pragma unroll
    for (int c = 0; c < 4; ++c)
      bfr[c] = *(const bf16x8*)(Bbuf + ((4 * wave + c) * 16 + m) * 40 + quad * 8);
#pragma unroll
    for (int rt = 0; rt < 5; ++rt) {
      bf16x8 a = *(const bf16x8*)(ldsA1 + (rt * 16 + m) * 40 + quad * 8);
#pragma unroll
      for (int c = 0; c < 4; ++c) {
        acc[rt][c] = __builtin_amdgcn_mfma_f32_16x16x32_bf16(a, bfr[c], z4, 0, 0, 0);
      }
    }
    // epilogue: relu + pair-packed bf16x2 writes (conflict-free b32)
#pragma unroll
    for (int rt = 0; rt < 5; ++rt)
#pragma unroll
      for (int c = 0; c < 4; ++c) {
        int col = (4 * wave + c) * 16 + m;
        float bv = b_other[col];
#pragma unroll
        for (int r = 0; r < 4; ++r) {
          float v = acc[rt][c][r] + bv;
          v = v > 0.f ? v : 0.f;
          unsigned u = bfbits(v);
          unsigned other = (unsigned)__shfl_xor((int)u, 1, 64);
          if ((m & 1) == 0) {
            int rowl = rt * 16 + quad * 4 + r;
            *(unsigned*)(ldsO + rowl * 264 + col) = u | (other << 16);
          }
        }
      }
  }
  __syncthreads();

  // ---- phase 2: k = relu(other_em @ WtK^T + b_k); scores = k.q/16
#pragma unroll
  for (int rt = 0; rt < 5; ++rt)
#pragma unroll
    for (int c = 0; c < 4; ++c) acc[rt][c] = z4;
  for (int ch = 0; ch < 8; ++ch) {
    const int kc = ch * 32;
    for (int p = tid; p < 1024; p += 256) {
      int n = p >> 2, f = p & 3;
      *(bf16x8*)(Bbuf + n * 40 + f * 8) =
          *(const bf16x8*)(WtK + (size_t)n * 256 + kc + f * 8);
    }
    __syncthreads();
    bf16x8 bfr[4];
#pragma unroll
    for (int c = 0; c < 4; ++c)
      bfr[c] = *(const bf16x8*)(Bbuf + ((4 * wave + c) * 16 + m) * 40 + quad * 8);
#pragma unroll
    for (int rt = 0; rt < 5; ++rt) {
      bf16x8 a = *(const bf16x8*)(ldsO + (rt * 16 + m) * 264 + kc + quad * 8);
#pragma unroll
      for (int c = 0; c < 4; ++c)
        acc[rt][c] = __builtin_amdgcn_mfma_f32_16x16x32_bf16(a, bfr[c], acc[rt][c], 0, 0, 0);
    }
    __syncthreads();   // protect Bbuf before next chunk's staging
  }
  // scores: in-lane over c, shuffle over m, partials per wave to LDS
#pragma unroll
  for (int rt = 0; rt < 5; ++rt) {
    float part[4] = {0.f, 0.f, 0.f, 0.f};
#pragma unroll
    for (int c = 0; c < 4; ++c) {
      int col = (4 * wave + c) * 16 + m;
      float bkv = b_k[col];
#pragma unroll
      for (int r = 0; r < 4; ++r) {
        int rowl = rt * 16 + quad * 4 + r;
        int br = rowl / 19; int bs = br > 3 ? 3 : br;
        float kv = acc[rt][c][r] + bkv;
        kv = kv > 0.f ? kv : 0.f;
        part[r] += kv * qh[bs * 256 + col];
      }
    }
#pragma unroll
    for (int r = 0; r < 4; ++r) {
      float p = part[r];
      p += __shfl_xor(p, 1, 64);
      p += __shfl_xor(p, 2, 64);
      p += __shfl_xor(p, 4, 64);
      p += __shfl_xor(p, 8, 64);
      if (m == 0) spart[wave * 96 + rt * 16 + quad * 4 + r] = p;
    }
  }
  __syncthreads();
  if (tid < 4) {
    float sc[19];
    float mx = -1e30f;
#pragma unroll
    for (int j = 0; j < 19; ++j) {
      int row = tid * 19 + j;
      float s = (spart[row] + spart[96 + row] + spart[192 + row] + spart[288 + row]) * 0.0625f;
      sc[j] = s; mx = fmaxf(mx, s);
    }
    float sum = 0.f;
#pragma unroll
    for (int j = 0; j < 19; ++j) { float e = __expf(sc[j] - mx); sc[j] = e; sum += e; }
    float inv = 1.f / sum;
#pragma unroll
    for (int j = 0; j < 19; ++j) {
      float a = sc[j] * inv;
      attl[tid * 19 + j] = a;
      att_out[(size_t)(b0 + tid) * 19 + j] = a;
    }
  }
  __syncthreads();

  // ---- phase 3: v = relu(other_em @ WtV1^T + sv); h = att . v
#pragma unroll
  for (int rt = 0; rt < 5; ++rt)
#pragma unroll
    for (int c = 0; c < 4; ++c) acc[rt][c] = z4;
  for (int ch = 0; ch < 8; ++ch) {
    const int kc = ch * 32;
    for (int p = tid; p < 1024; p += 256) {
      int n = p >> 2, f = p & 3;
      *(bf16x8*)(Bbuf + n * 40 + f * 8) =
          *(const bf16x8*)(WtV1 + (size_t)n * 256 + kc + f * 8);
    }
    __syncthreads();
    bf16x8 bfr[4];
#pragma unroll
    for (int c = 0; c < 4; ++c)
      bfr[c] = *(const bf16x8*)(Bbuf + ((4 * wave + c) * 16 + m) * 40 + quad * 8);
#pragma unroll
    for (int rt = 0; rt < 5; ++rt) {
      bf16x8 a = *(const bf16x8*)(ldsO + (rt * 16 + m) * 264 + kc + quad * 8);
#pragma unroll
      for (int c = 0; c < 4; ++c)
        acc[rt][c] = __builtin_amdgcn_mfma_f32_16x16x32_bf16(a, bfr[c], acc[rt][c], 0, 0, 0);
    }
    __syncthreads();
  }
  // epilogue: +sv, relu, *att, bucket into per-batch h, cross-lane reduce
  {
    float hacc[4][4];   // [c][batch]
#pragma unroll
    for (int c = 0; c < 4; ++c)
#pragma unroll
      for (int bb = 0; bb < 4; ++bb) hacc[c][bb] = 0.f;
#pragma unroll
    for (int rt = 0; rt < 5; ++rt)
#pragma unroll
      for (int c = 0; c < 4; ++c) {
        int col = (4 * wave + c) * 16 + m;
#pragma unroll
        for (int r = 0; r < 4; ++r) {
          int rowl = rt * 16 + quad * 4 + r;
          int br = rowl / 19; int bs = br > 3 ? 3 : br;
          float v = acc[rt][c][r] + svl[bs * 256 + col];
          v = v > 0.f ? v : 0.f;
          int ai = bs * 19 + (rowl - bs * 19);
          float hv = v * attl[ai < 96 ? ai : 95];
#pragma unroll
          for (int bb = 0; bb < 4; ++bb)
            hacc[c][bb] += (br == bb) ? hv : 0.f;
        }
      }
#pragma unroll
    for (int c = 0; c < 4; ++c)
#pragma unroll
      for (int bb = 0; bb < 4; ++bb) {
        float h = hacc[c][bb];
        h += __shfl_xor(h, 16, 64);
        h += __shfl_xor(h, 32, 64);
        if (quad == 0) qh[bb * 256 + (4 * wave + c) * 16 + m] = h;
      }
  }
  __syncthreads();
  for (int i = tid; i < 1024; i += 256)
    hb[(size_t)(b0 + (i >> 8)) * 256 + (i & 255)] = (bf16)qh[i];
}

// ---------------------------------------------------------------------------
extern "C" void kernel_launch(void* const* d_in, const int* in_sizes, int n_in,
                              void* d_out, int out_size, void* d_ws, size_t ws_size,
                              hipStream_t stream) {
  (void)in_sizes; (void)n_in; (void)out_size; (void)ws_size;
  const float* x      = (const float*)d_in[0];
  const float* eps    = (const float*)d_in[1];
  const float* W_mu   = (const float*)d_in[2];
  const float* b_mu   = (const float*)d_in[3];
  const float* W_var  = (const float*)d_in[4];
  const float* b_var  = (const float*)d_in[5];
  const float* W_self = (const float*)d_in[6];
  const float* b_self = (const float*)d_in[7];
  const float* W_other= (const float*)d_in[8];
  const float* b_other= (const float*)d_in[9];
  const float* W_q    = (const float*)d_in[10];
  const float* b_q    = (const float*)d_in[11];
  const float* W_k    = (const float*)d_in[12];
  const float* b_k    = (const float*)d_in[13];
  const float* W_v    = (const float*)d_in[14];
  const float* b_v    = (const float*)d_in[15];
  const float* W_a    = (const float*)d_in[16];
  const float* b_a    = (const float*)d_in[17];

  char* wsb = (char*)d_ws;
  bf16* WtMu    = (bf16*)(wsb + OFF_WT_MU);
  bf16* WtVar   = (bf16*)(wsb + OFF_WT_VAR);
  bf16* WtSelf  = (bf16*)(wsb + OFF_WT_SELF);
  bf16* WtOther = (bf16*)(wsb + OFF_WT_OTHER);
  bf16* WtQ     = (bf16*)(wsb + OFF_WT_Q);
  bf16* WtK     = (bf16*)(wsb + OFF_WT_K);
  bf16* WtV1    = (bf16*)(wsb + OFF_WT_V1);
  bf16* WtV2    = (bf16*)(wsb + OFF_WT_V2);
  bf16* WtA1    = (bf16*)(wsb + OFF_WT_A1);
  bf16* WtA2    = (bf16*)(wsb + OFF_WT_A2);
  bf16* zbuf    = (bf16*)(wsb + OFF_Z);
  bf16* selfbuf = (bf16*)(wsb + OFF_SELF);
  bf16* qbuf    = (bf16*)(wsb + OFF_Q);
  bf16* svbuf   = (bf16*)(wsb + OFF_SV);
  bf16* hbuf    = (bf16*)(wsb + OFF_H);

  float* out = (float*)d_out;
  float* att_out = out + (size_t)NB * 256;

  dim3 blk(256);
  wprep<<<dim3(160, 10), blk, 0, stream>>>(W_mu, W_var, W_self, W_other, W_q, W_k, W_v, W_a, wsb);
  // z = eps*exp(0.5*logvar)+mu  (fused mu/var GEMM, K=576)
  gemm_k<0, true><<<NB / 64, blk, 0, stream>>>(x, nullptr, 568, 576, 568,
                                               WtMu, WtVar, b_mu, b_var, eps, zbuf);
  // self_em = relu(x[:, :36] @ W_self + b_self)  (K=64, zero-padded weights)
  gemm_k<1, true><<<NB / 64, blk, 0, stream>>>(x, nullptr, 568, 64, 568,
                                               WtSelf, nullptr, b_self, nullptr, nullptr, selfbuf);
  // q = relu(z @ W_q + b_q)
  gemm_k<1, false><<<NB / 64, blk, 0, stream>>>(zbuf, nullptr, 256, 256, 256,
                                                WtQ, nullptr, b_q, nullptr, nullptr, qbuf);
  // sv = self_em @ W_v[256:] + b_v   (no relu)
  gemm_k<2, false><<<NB / 64, blk, 0, stream>>>(selfbuf, nullptr, 256, 256, 256,
                                                WtV2, nullptr, b_v, nullptr, nullptr, svbuf);
  // fused: other_em -> k -> scores -> softmax -> v -> h
  k_fused<<<NB / 4, blk, 0, stream>>>(x, qbuf, svbuf, WtOther, b_other, WtK, b_k,
                                      WtV1, att_out, hbuf);
  // out = relu([h; self_em] @ W_a + b_a)
  gemm_k<3, false><<<NB / 64, blk, 0, stream>>>(hbuf, selfbuf, 256, 256, 256,
                                                WtA1, WtA2, b_a, nullptr, nullptr, out);
}

// Round 4
// 410.079 us; speedup vs baseline: 2.7200x; 1.2842x over previous
//
#include <hip/hip_runtime.h>

typedef __bf16 bf16;
typedef __bf16 bf16x4 __attribute__((ext_vector_type(4)));
typedef __bf16 bf16x8 __attribute__((ext_vector_type(8)));
typedef float  f32x4  __attribute__((ext_vector_type(4)));

// Problem constants
#define NB    16384      // batch
#define NOBS  568
#define NH    256
#define NAG   19         // N_OTHER

// ws byte offsets (all 16B aligned)
#define OFF_WT_MU    0u          // [256][576] bf16 (flat [n][kpad])
#define OFF_WT_VAR   294912u     // [256][576]
#define OFF_WT_SELF  589824u     // [256][64]
#define OFF_WT_OTHER 622592u     // [256][32]  (chunk-major == flat at K=32)
#define OFF_WT_Q     638976u     // [256][256] flat
#define OFF_WT_K     770048u     // CHUNK-MAJOR [8][256][32]
#define OFF_WT_V1    901120u     // CHUNK-MAJOR [8][256][32]
#define OFF_WT_V2    1032192u    // flat
#define OFF_WT_A1    1163264u    // flat
#define OFF_WT_A2    1294336u    // flat
#define OFF_Z        1425408u    // [16384][256] bf16
#define OFF_SELF     9814016u
#define OFF_Q        18202624u
#define OFF_SV       26591232u   // bf16 (includes b_v)
#define OFF_H        34979840u

static __device__ __forceinline__ unsigned short bfbits(float v) {
  bf16 b = (bf16)v;
  union { bf16 b; unsigned short u; } cvt; cvt.b = b; return cvt.u;
}

// ---------------------------------------------------------------------------
// Weight prep: fp32 W[k][n] -> bf16. Flat: Wt[n][kpad] (zero-padded K).
// Chunked (for k_fused streaming): Wt[k/32][n][k%32] so a wave's B-frag
// loads are contiguous 64B runs.
// ---------------------------------------------------------------------------
__global__ __launch_bounds__(256) void wprep(
    const float* __restrict__ Wmu, const float* __restrict__ Wvar,
    const float* __restrict__ Wself, const float* __restrict__ Wother,
    const float* __restrict__ Wq, const float* __restrict__ Wk,
    const float* __restrict__ Wv, const float* __restrict__ Wa, char* wsb)
{
  const float* src; bf16* dst; int K, Kp; bool chunked = false;
  switch (blockIdx.y) {
    case 0: src = Wmu;        dst = (bf16*)(wsb + OFF_WT_MU);    K = 568; Kp = 576; break;
    case 1: src = Wvar;       dst = (bf16*)(wsb + OFF_WT_VAR);   K = 568; Kp = 576; break;
    case 2: src = Wself;      dst = (bf16*)(wsb + OFF_WT_SELF);  K = 36;  Kp = 64;  break;
    case 3: src = Wother;     dst = (bf16*)(wsb + OFF_WT_OTHER); K = 28;  Kp = 32;  break;
    case 4: src = Wq;         dst = (bf16*)(wsb + OFF_WT_Q);     K = 256; Kp = 256; break;
    case 5: src = Wk;         dst = (bf16*)(wsb + OFF_WT_K);     K = 256; Kp = 256; chunked = true; break;
    case 6: src = Wv;         dst = (bf16*)(wsb + OFF_WT_V1);    K = 256; Kp = 256; chunked = true; break;
    case 7: src = Wv + 65536; dst = (bf16*)(wsb + OFF_WT_V2);    K = 256; Kp = 256; break;
    case 8: src = Wa;         dst = (bf16*)(wsb + OFF_WT_A1);    K = 256; Kp = 256; break;
    default: src = Wa + 65536; dst = (bf16*)(wsb + OFF_WT_A2);   K = 256; Kp = 256; break;
  }
  int total = 256 * Kp;
  if (chunked) {
    for (int i = blockIdx.x * 256 + threadIdx.x; i < total; i += gridDim.x * 256) {
      int ch = i >> 13, n = (i >> 5) & 255, kk = i & 31;
      int k = ch * 32 + kk;
      dst[i] = (bf16)src[k * 256 + n];
    }
  } else {
    for (int i = blockIdx.x * 256 + threadIdx.x; i < total; i += gridDim.x * 256) {
      int n = i / Kp, k = i - n * Kp;
      dst[i] = (k < K) ? (bf16)src[k * 256 + n] : (bf16)0.f;
    }
  }
}

// ---------------------------------------------------------------------------
// Generic 64-row GEMM, BK=32 (LDS 26/46 KB -> 2-3 blocks/CU).
// Wave w owns rows [w*16,w*16+16) x all 256 cols.
// EMODE: 0 = Z (dual Wt: mu & logvar -> z bf16), 1 = relu->bf16,
//        2 = +bias->bf16 (no relu), 3 = dual-A relu->f32 (final out)
// ---------------------------------------------------------------------------
template<int EMODE, bool AF32>
__global__ __launch_bounds__(256, 2) void gemm_k(
    const void* __restrict__ Aptr, const void* __restrict__ A2ptr,
    int lda, int K, int Klimit,
    const bf16* __restrict__ Wt, const bf16* __restrict__ Wt2,
    const float* __restrict__ bias, const float* __restrict__ bias2,
    const float* __restrict__ epsp, void* __restrict__ outp)
{
  constexpr bool DUALB = (EMODE == 0);
  constexpr bool DUALA = (EMODE == 3);
  __shared__ bf16 ldsA[64 * 40];
  __shared__ bf16 ldsB[256 * 40];
  __shared__ bf16 ldsB2[DUALB ? 256 * 40 : 8];

  const int tid = threadIdx.x;
  const int wave = tid >> 6;
  const int lane = tid & 63;
  const int quad = lane >> 4;
  const int m = lane & 15;
  const int rowbase = blockIdx.x * 64;

  f32x4 acc[16];
  f32x4 accB[DUALB ? 16 : 1];
  const f32x4 z4 = {0.f, 0.f, 0.f, 0.f};
#pragma unroll
  for (int ct = 0; ct < 16; ++ct) acc[ct] = z4;
  if constexpr (DUALB) {
#pragma unroll
    for (int ct = 0; ct < 16; ++ct) accB[ct] = z4;
  }

  const int npass = DUALA ? 2 : 1;
  for (int pass = 0; pass < npass; ++pass) {
    const void* Ap = (pass == 0) ? Aptr : A2ptr;
    const bf16* Wp = (pass == 0) ? Wt : Wt2;
    for (int kc = 0; kc < K; kc += 32) {
      __syncthreads();
      if constexpr (AF32) {
        const float* Af = (const float*)Ap;
#pragma unroll
        for (int it = 0; it < 2; ++it) {
          int p = tid + 256 * it;          // 512 float4 segments
          int r = p >> 3, fs = p & 7;
          int k = kc + fs * 4;
          const float* src = Af + (size_t)(rowbase + r) * lda + k;
          float v0, v1, v2, v3;
          if (k + 4 <= Klimit) {
            float4 v = *(const float4*)src;
            v0 = v.x; v1 = v.y; v2 = v.z; v3 = v.w;
          } else {
            v0 = (k + 0 < Klimit) ? src[0] : 0.f;
            v1 = (k + 1 < Klimit) ? src[1] : 0.f;
            v2 = (k + 2 < Klimit) ? src[2] : 0.f;
            v3 = (k + 3 < Klimit) ? src[3] : 0.f;
          }
          bf16x4 o = {(bf16)v0, (bf16)v1, (bf16)v2, (bf16)v3};
          *(bf16x4*)(ldsA + r * 40 + fs * 4) = o;
        }
      } else {
        const bf16* Ab = (const bf16*)Ap;
        {
          int p = tid;                      // 256 bf16x8 segments
          int r = p >> 2, f = p & 3;
          *(bf16x8*)(ldsA + r * 40 + f * 8) =
              *(const bf16x8*)(Ab + (size_t)(rowbase + r) * lda + kc + f * 8);
        }
      }
#pragma unroll
      for (int it = 0; it < 4; ++it) {
        int p = tid + 256 * it;             // 1024 bf16x8 segments
        int n = p >> 2, f = p & 3;
        *(bf16x8*)(ldsB + n * 40 + f * 8) =
            *(const bf16x8*)(Wp + (size_t)n * K + kc + f * 8);
      }
      if constexpr (DUALB) {
#pragma unroll
        for (int it = 0; it < 4; ++it) {
          int p = tid + 256 * it;
          int n = p >> 2, f = p & 3;
          *(bf16x8*)(ldsB2 + n * 40 + f * 8) =
              *(const bf16x8*)(Wt2 + (size_t)n * K + kc + f * 8);
        }
      }
      __syncthreads();
      bf16x8 afrag = *(const bf16x8*)(ldsA + (wave * 16 + m) * 40 + quad * 8);
#pragma unroll
      for (int ct = 0; ct < 16; ++ct) {
        bf16x8 bfrag = *(const bf16x8*)(ldsB + (ct * 16 + m) * 40 + quad * 8);
        acc[ct] = __builtin_amdgcn_mfma_f32_16x16x32_bf16(afrag, bfrag, acc[ct], 0, 0, 0);
        if constexpr (DUALB) {
          bf16x8 b2 = *(const bf16x8*)(ldsB2 + (ct * 16 + m) * 40 + quad * 8);
          accB[ct] = __builtin_amdgcn_mfma_f32_16x16x32_bf16(afrag, b2, accB[ct], 0, 0, 0);
        }
      }
    }
  }
#pragma unroll
  for (int ct = 0; ct < 16; ++ct) {
    const int col = ct * 16 + m;
    const float bv = bias[col];
#pragma unroll
    for (int r = 0; r < 4; ++r) {
      const size_t row = (size_t)rowbase + wave * 16 + quad * 4 + r;
      float v = acc[ct][r] + bv;
      if constexpr (EMODE == 0) {
        float lv = accB[ct][r] + bias2[col];
        float zz = epsp[row * 256 + col] * __expf(0.5f * lv) + v;
        ((bf16*)outp)[row * 256 + col] = (bf16)zz;
      } else if constexpr (EMODE == 1) {
        ((bf16*)outp)[row * 256 + col] = (bf16)(v > 0.f ? v : 0.f);
      } else if constexpr (EMODE == 2) {
        ((bf16*)outp)[row * 256 + col] = (bf16)v;
      } else {
        ((float*)outp)[row * 256 + col] = (v > 0.f ? v : 0.f);
      }
    }
  }
}

// ---------------------------------------------------------------------------
// Fused attention: other_em -> {k,v} (merged K-loop) -> scores -> softmax
// -> h, one kernel. Block = 4 batches = 76 agent rows (padded 80 = 5 tiles).
// Wave w owns the 64-col strip (4 col-tiles) x ALL 5 row-tiles.
// B-fragments stream DIRECTLY from global (chunk-major weights, L2-hot):
// no B staging, no barriers in the K-loop; k-acc and v-acc in one pass.
// ---------------------------------------------------------------------------
__global__ __launch_bounds__(256, 2) void k_fused(
    const float* __restrict__ x, const bf16* __restrict__ qb,
    const bf16* __restrict__ svb,
    const bf16* __restrict__ WtOther, const float* __restrict__ b_other,
    const bf16* __restrict__ WtKc, const float* __restrict__ b_k,
    const bf16* __restrict__ WtVc,
    float* __restrict__ att_out, bf16* __restrict__ hb)
{
  __shared__ bf16 ldsO[80 * 264];     // other_em (stride 264: 16B-group stride 33 -> conflict-free frag reads)
  __shared__ bf16 ldsA1[80 * 40];     // agents_info tile
  __shared__ float qh[1024];          // q, later h partials
  __shared__ float svl[1024];         // sv (self-half of v, incl. b_v)
  __shared__ float spart[4 * 96];     // per-wave score partials
  __shared__ float attl[96];          // att weights per row

  const int tid = threadIdx.x, wave = tid >> 6, lane = tid & 63;
  const int quad = lane >> 4, m = lane & 15;
  const int b0 = blockIdx.x * 4;

  // ---- phase 0: stage q, sv, agents_info
  for (int i = tid; i < 1024; i += 256) {
    qh[i]  = (float)qb[(size_t)b0 * 256 + i];
    svl[i] = (float)svb[(size_t)b0 * 256 + i];
  }
  for (int i = tid; i < 80 * 16; i += 256) {
    int r = i >> 4, kk = (i & 15) * 2;
    float v0 = 0.f, v1 = 0.f;
    if (r < 76) {
      int bb = b0 + r / 19, n = r % 19;
      const float* base = x + (size_t)bb * NOBS + 36 + n * 28;
      if (kk < 28) v0 = base[kk];
      if (kk + 1 < 28) v1 = base[kk + 1];
    }
    unsigned u0 = bfbits(v0), u1 = bfbits(v1);
    *(unsigned*)(ldsA1 + r * 40 + kk) = u0 | (u1 << 16);
  }
  __syncthreads();

  const f32x4 z4 = {0.f, 0.f, 0.f, 0.f};

  // ---- phase 1: other_em = relu(A1 @ WtOther^T + b_other), K=32
  {
    f32x4 acc1[5][4];
    bf16x8 bfr[4];
#pragma unroll
    for (int c = 0; c < 4; ++c)
      bfr[c] = *(const bf16x8*)(WtOther + ((4 * wave + c) * 16 + m) * 32 + quad * 8);
#pragma unroll
    for (int rt = 0; rt < 5; ++rt) {
      bf16x8 a = *(const bf16x8*)(ldsA1 + (rt * 16 + m) * 40 + quad * 8);
#pragma unroll
      for (int c = 0; c < 4; ++c)
        acc1[rt][c] = __builtin_amdgcn_mfma_f32_16x16x32_bf16(a, bfr[c], z4, 0, 0, 0);
    }
#pragma unroll
    for (int rt = 0; rt < 5; ++rt)
#pragma unroll
      for (int c = 0; c < 4; ++c) {
        int col = (4 * wave + c) * 16 + m;
        float bv = b_other[col];
#pragma unroll
        for (int r = 0; r < 4; ++r) {
          float v = acc1[rt][c][r] + bv;
          v = v > 0.f ? v : 0.f;
          unsigned u = bfbits(v);
          unsigned other = (unsigned)__shfl_xor((int)u, 1, 64);
          if ((m & 1) == 0) {
            int rowl = rt * 16 + quad * 4 + r;
            *(unsigned*)(ldsO + rowl * 264 + col) = u | (other << 16);
          }
        }
      }
  }
  __syncthreads();

  // ---- phase 2+3 merged: k and v accumulated in ONE pass, no barriers.
  f32x4 aK[5][4], aV[5][4];
#pragma unroll
  for (int rt = 0; rt < 5; ++rt)
#pragma unroll
    for (int c = 0; c < 4; ++c) { aK[rt][c] = z4; aV[rt][c] = z4; }

  for (int ch = 0; ch < 8; ++ch) {
    const int kc = ch * 32;
    bf16x8 bK[4], bV[4];
#pragma unroll
    for (int c = 0; c < 4; ++c) {
      const size_t fo = (size_t)ch * 8192 + ((4 * wave + c) * 16 + m) * 32 + quad * 8;
      bK[c] = *(const bf16x8*)(WtKc + fo);
      bV[c] = *(const bf16x8*)(WtVc + fo);
    }
#pragma unroll
    for (int rt = 0; rt < 5; ++rt) {
      bf16x8 a = *(const bf16x8*)(ldsO + (rt * 16 + m) * 264 + kc + quad * 8);
#pragma unroll
      for (int c = 0; c < 4; ++c) {
        aK[rt][c] = __builtin_amdgcn_mfma_f32_16x16x32_bf16(a, bK[c], aK[rt][c], 0, 0, 0);
        aV[rt][c] = __builtin_amdgcn_mfma_f32_16x16x32_bf16(a, bV[c], aV[rt][c], 0, 0, 0);
      }
    }
  }

  // ---- scores: relu(k)+b_k dot q, reduce across lanes then waves
#pragma unroll
  for (int rt = 0; rt < 5; ++rt) {
    float part[4] = {0.f, 0.f, 0.f, 0.f};
#pragma unroll
    for (int c = 0; c < 4; ++c) {
      int col = (4 * wave + c) * 16 + m;
      float bkv = b_k[col];
#pragma unroll
      for (int r = 0; r < 4; ++r) {
        int rowl = rt * 16 + quad * 4 + r;
        int br = rowl / 19; int bs = br > 3 ? 3 : br;
        float kv = aK[rt][c][r] + bkv;
        kv = kv > 0.f ? kv : 0.f;
        part[r] += kv * qh[bs * 256 + col];
      }
    }
#pragma unroll
    for (int r = 0; r < 4; ++r) {
      float p = part[r];
      p += __shfl_xor(p, 1, 64);
      p += __shfl_xor(p, 2, 64);
      p += __shfl_xor(p, 4, 64);
      p += __shfl_xor(p, 8, 64);
      if (m == 0) spart[wave * 96 + rt * 16 + quad * 4 + r] = p;
    }
  }
  __syncthreads();
  if (tid < 4) {
    float sc[19];
    float mx = -1e30f;
#pragma unroll
    for (int j = 0; j < 19; ++j) {
      int row = tid * 19 + j;
      float s = (spart[row] + spart[96 + row] + spart[192 + row] + spart[288 + row]) * 0.0625f;
      sc[j] = s; mx = fmaxf(mx, s);
    }
    float sum = 0.f;
#pragma unroll
    for (int j = 0; j < 19; ++j) { float e = __expf(sc[j] - mx); sc[j] = e; sum += e; }
    float inv = 1.f / sum;
#pragma unroll
    for (int j = 0; j < 19; ++j) {
      float a = sc[j] * inv;
      attl[tid * 19 + j] = a;
      att_out[(size_t)(b0 + tid) * 19 + j] = a;
    }
  }
  __syncthreads();

  // ---- v epilogue: +sv, relu, *att, bucket into per-batch h, reduce
  {
    float hacc[4][4];   // [c][batch]
#pragma unroll
    for (int c = 0; c < 4; ++c)
#pragma unroll
      for (int bb = 0; bb < 4; ++bb) hacc[c][bb] = 0.f;
#pragma unroll
    for (int rt = 0; rt < 5; ++rt)
#pragma unroll
      for (int c = 0; c < 4; ++c) {
        int col = (4 * wave + c) * 16 + m;
#pragma unroll
        for (int r = 0; r < 4; ++r) {
          int rowl = rt * 16 + quad * 4 + r;
          int br = rowl / 19; int bs = br > 3 ? 3 : br;
          float v = aV[rt][c][r] + svl[bs * 256 + col];
          v = v > 0.f ? v : 0.f;
          int ai = bs * 19 + (rowl - bs * 19);
          float hv = v * attl[ai < 96 ? ai : 95];
#pragma unroll
          for (int bb = 0; bb < 4; ++bb)
            hacc[c][bb] += (br == bb) ? hv : 0.f;
        }
      }
#pragma unroll
    for (int c = 0; c < 4; ++c)
#pragma unroll
      for (int bb = 0; bb < 4; ++bb) {
        float h = hacc[c][bb];
        h += __shfl_xor(h, 16, 64);
        h += __shfl_xor(h, 32, 64);
        if (quad == 0) qh[bb * 256 + (4 * wave + c) * 16 + m] = h;
      }
  }
  __syncthreads();
  for (int i = tid; i < 1024; i += 256)
    hb[(size_t)(b0 + (i >> 8)) * 256 + (i & 255)] = (bf16)qh[i];
}

// ---------------------------------------------------------------------------
extern "C" void kernel_launch(void* const* d_in, const int* in_sizes, int n_in,
                              void* d_out, int out_size, void* d_ws, size_t ws_size,
                              hipStream_t stream) {
  (void)in_sizes; (void)n_in; (void)out_size; (void)ws_size;
  const float* x      = (const float*)d_in[0];
  const float* eps    = (const float*)d_in[1];
  const float* W_mu   = (const float*)d_in[2];
  const float* b_mu   = (const float*)d_in[3];
  const float* W_var  = (const float*)d_in[4];
  const float* b_var  = (const float*)d_in[5];
  const float* W_self = (const float*)d_in[6];
  const float* b_self = (const float*)d_in[7];
  const float* W_other= (const float*)d_in[8];
  const float* b_other= (const float*)d_in[9];
  const float* W_q    = (const float*)d_in[10];
  const float* b_q    = (const float*)d_in[11];
  const float* W_k    = (const float*)d_in[12];
  const float* b_k    = (const float*)d_in[13];
  const float* W_v    = (const float*)d_in[14];
  const float* b_v    = (const float*)d_in[15];
  const float* W_a    = (const float*)d_in[16];
  const float* b_a    = (const float*)d_in[17];

  char* wsb = (char*)d_ws;
  bf16* WtMu    = (bf16*)(wsb + OFF_WT_MU);
  bf16* WtVar   = (bf16*)(wsb + OFF_WT_VAR);
  bf16* WtSelf  = (bf16*)(wsb + OFF_WT_SELF);
  bf16* WtOther = (bf16*)(wsb + OFF_WT_OTHER);
  bf16* WtQ     = (bf16*)(wsb + OFF_WT_Q);
  bf16* WtK     = (bf16*)(wsb + OFF_WT_K);
  bf16* WtV1    = (bf16*)(wsb + OFF_WT_V1);
  bf16* WtV2    = (bf16*)(wsb + OFF_WT_V2);
  bf16* WtA1    = (bf16*)(wsb + OFF_WT_A1);
  bf16* WtA2    = (bf16*)(wsb + OFF_WT_A2);
  bf16* zbuf    = (bf16*)(wsb + OFF_Z);
  bf16* selfbuf = (bf16*)(wsb + OFF_SELF);
  bf16* qbuf    = (bf16*)(wsb + OFF_Q);
  bf16* svbuf   = (bf16*)(wsb + OFF_SV);
  bf16* hbuf    = (bf16*)(wsb + OFF_H);

  float* out = (float*)d_out;
  float* att_out = out + (size_t)NB * 256;

  dim3 blk(256);
  wprep<<<dim3(160, 10), blk, 0, stream>>>(W_mu, W_var, W_self, W_other, W_q, W_k, W_v, W_a, wsb);
  // z = eps*exp(0.5*logvar)+mu  (fused mu/var GEMM, K=576)
  gemm_k<0, true><<<NB / 64, blk, 0, stream>>>(x, nullptr, 568, 576, 568,
                                               WtMu, WtVar, b_mu, b_var, eps, zbuf);
  // self_em = relu(x[:, :36] @ W_self + b_self)  (K=64, zero-padded weights)
  gemm_k<1, true><<<NB / 64, blk, 0, stream>>>(x, nullptr, 568, 64, 568,
                                               WtSelf, nullptr, b_self, nullptr, nullptr, selfbuf);
  // q = relu(z @ W_q + b_q)
  gemm_k<1, false><<<NB / 64, blk, 0, stream>>>(zbuf, nullptr, 256, 256, 256,
                                                WtQ, nullptr, b_q, nullptr, nullptr, qbuf);
  // sv = self_em @ W_v[256:] + b_v   (no relu)
  gemm_k<2, false><<<NB / 64, blk, 0, stream>>>(selfbuf, nullptr, 256, 256, 256,
                                                WtV2, nullptr, b_v, nullptr, nullptr, svbuf);
  // fused: other_em -> {k,v} -> scores -> softmax -> h
  k_fused<<<NB / 4, blk, 0, stream>>>(x, qbuf, svbuf, WtOther, b_other, WtK, b_k,
                                      WtV1, att_out, hbuf);
  // out = relu([h; self_em] @ W_a + b_a)
  gemm_k<3, false><<<NB / 64, blk, 0, stream>>>(hbuf, selfbuf, 256, 256, 256,
                                                WtA1, WtA2, b_a, nullptr, nullptr, out);
}

// Round 5
// 392.634 us; speedup vs baseline: 2.8409x; 1.0444x over previous
//
#include <hip/hip_runtime.h>

typedef __bf16 bf16;
typedef __bf16 bf16x4 __attribute__((ext_vector_type(4)));
typedef __bf16 bf16x8 __attribute__((ext_vector_type(8)));
typedef float  f32x4  __attribute__((ext_vector_type(4)));

// Problem constants
#define NB    16384      // batch
#define NOBS  568
#define NH    256
#define NAG   19         // N_OTHER

// ws byte offsets (all 16B aligned)
#define OFF_WT_MU    0u          // [256][576] bf16 (flat [n][kpad])
#define OFF_WT_VAR   294912u     // [256][576]
#define OFF_WT_SELF  589824u     // [256][64]
#define OFF_WT_OTHER 622592u     // [256][32]  (chunk-major == flat at K=32)
#define OFF_WT_Q     638976u     // [256][256] flat
#define OFF_WT_K     770048u     // CHUNK-MAJOR [8][256][32]
#define OFF_WT_V1    901120u     // CHUNK-MAJOR [8][256][32]
#define OFF_WT_V2    1032192u    // flat
#define OFF_WT_A1    1163264u    // flat
#define OFF_WT_A2    1294336u    // flat
#define OFF_Z        1425408u    // [16384][256] bf16
#define OFF_SELF     9814016u
#define OFF_Q        18202624u
#define OFF_SV       26591232u   // bf16 (includes b_v)
#define OFF_H        34979840u

static __device__ __forceinline__ unsigned short bfbits(float v) {
  bf16 b = (bf16)v;
  union { bf16 b; unsigned short u; } cvt; cvt.b = b; return cvt.u;
}

// ---------------------------------------------------------------------------
// Weight prep: fp32 W[k][n] -> bf16. Flat: Wt[n][kpad] (zero-padded K).
// Chunked (for k_fused streaming): Wt[k/32][n][k%32] so a wave's B-frag
// loads are contiguous 64B runs.
// ---------------------------------------------------------------------------
__global__ __launch_bounds__(256) void wprep(
    const float* __restrict__ Wmu, const float* __restrict__ Wvar,
    const float* __restrict__ Wself, const float* __restrict__ Wother,
    const float* __restrict__ Wq, const float* __restrict__ Wk,
    const float* __restrict__ Wv, const float* __restrict__ Wa, char* wsb)
{
  const float* src; bf16* dst; int K, Kp; bool chunked = false;
  switch (blockIdx.y) {
    case 0: src = Wmu;        dst = (bf16*)(wsb + OFF_WT_MU);    K = 568; Kp = 576; break;
    case 1: src = Wvar;       dst = (bf16*)(wsb + OFF_WT_VAR);   K = 568; Kp = 576; break;
    case 2: src = Wself;      dst = (bf16*)(wsb + OFF_WT_SELF);  K = 36;  Kp = 64;  break;
    case 3: src = Wother;     dst = (bf16*)(wsb + OFF_WT_OTHER); K = 28;  Kp = 32;  break;
    case 4: src = Wq;         dst = (bf16*)(wsb + OFF_WT_Q);     K = 256; Kp = 256; break;
    case 5: src = Wk;         dst = (bf16*)(wsb + OFF_WT_K);     K = 256; Kp = 256; chunked = true; break;
    case 6: src = Wv;         dst = (bf16*)(wsb + OFF_WT_V1);    K = 256; Kp = 256; chunked = true; break;
    case 7: src = Wv + 65536; dst = (bf16*)(wsb + OFF_WT_V2);    K = 256; Kp = 256; break;
    case 8: src = Wa;         dst = (bf16*)(wsb + OFF_WT_A1);    K = 256; Kp = 256; break;
    default: src = Wa + 65536; dst = (bf16*)(wsb + OFF_WT_A2);   K = 256; Kp = 256; break;
  }
  int total = 256 * Kp;
  if (chunked) {
    for (int i = blockIdx.x * 256 + threadIdx.x; i < total; i += gridDim.x * 256) {
      int ch = i >> 13, n = (i >> 5) & 255, kk = i & 31;
      int k = ch * 32 + kk;
      dst[i] = (bf16)src[k * 256 + n];
    }
  } else {
    for (int i = blockIdx.x * 256 + threadIdx.x; i < total; i += gridDim.x * 256) {
      int n = i / Kp, k = i - n * Kp;
      dst[i] = (k < K) ? (bf16)src[k * 256 + n] : (bf16)0.f;
    }
  }
}

// ---------------------------------------------------------------------------
// Generic 64-row GEMM, BK=32 (LDS 26/46 KB -> 2-3 blocks/CU).
// Wave w owns rows [w*16,w*16+16) x all 256 cols.
// EMODE: 0 = Z (dual Wt: mu & logvar -> z bf16), 1 = relu->bf16,
//        2 = +bias->bf16 (no relu), 3 = dual-A relu->f32 (final out)
// ---------------------------------------------------------------------------
template<int EMODE, bool AF32>
__global__ __launch_bounds__(256, 2) void gemm_k(
    const void* __restrict__ Aptr, const void* __restrict__ A2ptr,
    int lda, int K, int Klimit,
    const bf16* __restrict__ Wt, const bf16* __restrict__ Wt2,
    const float* __restrict__ bias, const float* __restrict__ bias2,
    const float* __restrict__ epsp, void* __restrict__ outp)
{
  constexpr bool DUALB = (EMODE == 0);
  constexpr bool DUALA = (EMODE == 3);
  __shared__ bf16 ldsA[64 * 40];
  __shared__ bf16 ldsB[256 * 40];
  __shared__ bf16 ldsB2[DUALB ? 256 * 40 : 8];

  const int tid = threadIdx.x;
  const int wave = tid >> 6;
  const int lane = tid & 63;
  const int quad = lane >> 4;
  const int m = lane & 15;
  const int rowbase = blockIdx.x * 64;

  f32x4 acc[16];
  f32x4 accB[DUALB ? 16 : 1];
  const f32x4 z4 = {0.f, 0.f, 0.f, 0.f};
#pragma unroll
  for (int ct = 0; ct < 16; ++ct) acc[ct] = z4;
  if constexpr (DUALB) {
#pragma unroll
    for (int ct = 0; ct < 16; ++ct) accB[ct] = z4;
  }

  const int npass = DUALA ? 2 : 1;
  for (int pass = 0; pass < npass; ++pass) {
    const void* Ap = (pass == 0) ? Aptr : A2ptr;
    const bf16* Wp = (pass == 0) ? Wt : Wt2;
    for (int kc = 0; kc < K; kc += 32) {
      __syncthreads();
      if constexpr (AF32) {
        const float* Af = (const float*)Ap;
#pragma unroll
        for (int it = 0; it < 2; ++it) {
          int p = tid + 256 * it;          // 512 float4 segments
          int r = p >> 3, fs = p & 7;
          int k = kc + fs * 4;
          const float* src = Af + (size_t)(rowbase + r) * lda + k;
          float v0, v1, v2, v3;
          if (k + 4 <= Klimit) {
            float4 v = *(const float4*)src;
            v0 = v.x; v1 = v.y; v2 = v.z; v3 = v.w;
          } else {
            v0 = (k + 0 < Klimit) ? src[0] : 0.f;
            v1 = (k + 1 < Klimit) ? src[1] : 0.f;
            v2 = (k + 2 < Klimit) ? src[2] : 0.f;
            v3 = (k + 3 < Klimit) ? src[3] : 0.f;
          }
          bf16x4 o = {(bf16)v0, (bf16)v1, (bf16)v2, (bf16)v3};
          *(bf16x4*)(ldsA + r * 40 + fs * 4) = o;
        }
      } else {
        const bf16* Ab = (const bf16*)Ap;
        {
          int p = tid;                      // 256 bf16x8 segments
          int r = p >> 2, f = p & 3;
          *(bf16x8*)(ldsA + r * 40 + f * 8) =
              *(const bf16x8*)(Ab + (size_t)(rowbase + r) * lda + kc + f * 8);
        }
      }
#pragma unroll
      for (int it = 0; it < 4; ++it) {
        int p = tid + 256 * it;             // 1024 bf16x8 segments
        int n = p >> 2, f = p & 3;
        *(bf16x8*)(ldsB + n * 40 + f * 8) =
            *(const bf16x8*)(Wp + (size_t)n * K + kc + f * 8);
      }
      if constexpr (DUALB) {
#pragma unroll
        for (int it = 0; it < 4; ++it) {
          int p = tid + 256 * it;
          int n = p >> 2, f = p & 3;
          *(bf16x8*)(ldsB2 + n * 40 + f * 8) =
              *(const bf16x8*)(Wt2 + (size_t)n * K + kc + f * 8);
        }
      }
      __syncthreads();
      bf16x8 afrag = *(const bf16x8*)(ldsA + (wave * 16 + m) * 40 + quad * 8);
#pragma unroll
      for (int ct = 0; ct < 16; ++ct) {
        bf16x8 bfrag = *(const bf16x8*)(ldsB + (ct * 16 + m) * 40 + quad * 8);
        acc[ct] = __builtin_amdgcn_mfma_f32_16x16x32_bf16(afrag, bfrag, acc[ct], 0, 0, 0);
        if constexpr (DUALB) {
          bf16x8 b2 = *(const bf16x8*)(ldsB2 + (ct * 16 + m) * 40 + quad * 8);
          accB[ct] = __builtin_amdgcn_mfma_f32_16x16x32_bf16(afrag, b2, accB[ct], 0, 0, 0);
        }
      }
    }
  }
#pragma unroll
  for (int ct = 0; ct < 16; ++ct) {
    const int col = ct * 16 + m;
    const float bv = bias[col];
#pragma unroll
    for (int r = 0; r < 4; ++r) {
      const size_t row = (size_t)rowbase + wave * 16 + quad * 4 + r;
      float v = acc[ct][r] + bv;
      if constexpr (EMODE == 0) {
        float lv = accB[ct][r] + bias2[col];
        float zz = epsp[row * 256 + col] * __expf(0.5f * lv) + v;
        ((bf16*)outp)[row * 256 + col] = (bf16)zz;
      } else if constexpr (EMODE == 1) {
        ((bf16*)outp)[row * 256 + col] = (bf16)(v > 0.f ? v : 0.f);
      } else if constexpr (EMODE == 2) {
        ((bf16*)outp)[row * 256 + col] = (bf16)v;
      } else {
        ((float*)outp)[row * 256 + col] = (v > 0.f ? v : 0.f);
      }
    }
  }
}

// ---------------------------------------------------------------------------
// Fused attention: other_em -> k -> scores -> softmax -> v -> h, one kernel.
// Block = 4 batches = 76 agent rows (padded 80 = 5 tiles of 16).
// Wave w owns the 64-col strip (4 col-tiles) x ALL 5 row-tiles.
// B-fragments stream DIRECTLY from global (chunk-major weights, L2-hot):
// no B staging, no barriers in either K-loop.
// TWO SEQUENTIAL PASSES (K then V): peak live accumulators = 80 f32, not
// 160 -- the round-4 merged loop spilled MFMA accumulators to scratch
// (WRITE_SIZE 79 MB, RMW-paced at 525 GB/s).
// ---------------------------------------------------------------------------
__global__ __launch_bounds__(256, 2) void k_fused(
    const float* __restrict__ x, const bf16* __restrict__ qb,
    const bf16* __restrict__ svb,
    const bf16* __restrict__ WtOther, const float* __restrict__ b_other,
    const bf16* __restrict__ WtKc, const float* __restrict__ b_k,
    const bf16* __restrict__ WtVc,
    float* __restrict__ att_out, bf16* __restrict__ hb)
{
  __shared__ bf16 ldsO[80 * 264];     // other_em (16B-group stride 33 -> conflict-free frag reads)
  __shared__ bf16 ldsA1[80 * 40];     // agents_info tile
  __shared__ float qh[1024];          // q, later h partials
  __shared__ float svl[1024];         // sv (self-half of v, incl. b_v)
  __shared__ float spart[4 * 96];     // per-wave score partials
  __shared__ float attl[96];          // att weights per row

  const int tid = threadIdx.x, wave = tid >> 6, lane = tid & 63;
  const int quad = lane >> 4, m = lane & 15;
  const int b0 = blockIdx.x * 4;

  // ---- phase 0: stage q, sv, agents_info
  for (int i = tid; i < 1024; i += 256) {
    qh[i]  = (float)qb[(size_t)b0 * 256 + i];
    svl[i] = (float)svb[(size_t)b0 * 256 + i];
  }
  for (int i = tid; i < 80 * 16; i += 256) {
    int r = i >> 4, kk = (i & 15) * 2;
    float v0 = 0.f, v1 = 0.f;
    if (r < 76) {
      int bb = b0 + r / 19, n = r % 19;
      const float* base = x + (size_t)bb * NOBS + 36 + n * 28;
      if (kk < 28) v0 = base[kk];
      if (kk + 1 < 28) v1 = base[kk + 1];
    }
    unsigned u0 = bfbits(v0), u1 = bfbits(v1);
    *(unsigned*)(ldsA1 + r * 40 + kk) = u0 | (u1 << 16);
  }
  __syncthreads();

  const f32x4 z4 = {0.f, 0.f, 0.f, 0.f};

  // ---- phase 1: other_em = relu(A1 @ WtOther^T + b_other), K=32
  {
    f32x4 acc1[5][4];
    bf16x8 bfr[4];
#pragma unroll
    for (int c = 0; c < 4; ++c)
      bfr[c] = *(const bf16x8*)(WtOther + ((4 * wave + c) * 16 + m) * 32 + quad * 8);
#pragma unroll
    for (int rt = 0; rt < 5; ++rt) {
      bf16x8 a = *(const bf16x8*)(ldsA1 + (rt * 16 + m) * 40 + quad * 8);
#pragma unroll
      for (int c = 0; c < 4; ++c)
        acc1[rt][c] = __builtin_amdgcn_mfma_f32_16x16x32_bf16(a, bfr[c], z4, 0, 0, 0);
    }
#pragma unroll
    for (int rt = 0; rt < 5; ++rt)
#pragma unroll
      for (int c = 0; c < 4; ++c) {
        int col = (4 * wave + c) * 16 + m;
        float bv = b_other[col];
#pragma unroll
        for (int r = 0; r < 4; ++r) {
          float v = acc1[rt][c][r] + bv;
          v = v > 0.f ? v : 0.f;
          unsigned u = bfbits(v);
          unsigned other = (unsigned)__shfl_xor((int)u, 1, 64);
          if ((m & 1) == 0) {
            int rowl = rt * 16 + quad * 4 + r;
            *(unsigned*)(ldsO + rowl * 264 + col) = u | (other << 16);
          }
        }
      }
  }
  __syncthreads();

  // ---- pass K: k-accumulate, barrier-free (B direct from global)
  {
    f32x4 aK[5][4];
#pragma unroll
    for (int rt = 0; rt < 5; ++rt)
#pragma unroll
      for (int c = 0; c < 4; ++c) aK[rt][c] = z4;

    for (int ch = 0; ch < 8; ++ch) {
      const int kc = ch * 32;
      bf16x8 bK[4];
#pragma unroll
      for (int c = 0; c < 4; ++c)
        bK[c] = *(const bf16x8*)(WtKc + (size_t)ch * 8192 + ((4 * wave + c) * 16 + m) * 32 + quad * 8);
#pragma unroll
      for (int rt = 0; rt < 5; ++rt) {
        bf16x8 a = *(const bf16x8*)(ldsO + (rt * 16 + m) * 264 + kc + quad * 8);
#pragma unroll
        for (int c = 0; c < 4; ++c)
          aK[rt][c] = __builtin_amdgcn_mfma_f32_16x16x32_bf16(a, bK[c], aK[rt][c], 0, 0, 0);
      }
    }

    // scores: relu(k)+b_k dot q, reduce across lanes then waves
#pragma unroll
    for (int rt = 0; rt < 5; ++rt) {
      float part[4] = {0.f, 0.f, 0.f, 0.f};
#pragma unroll
      for (int c = 0; c < 4; ++c) {
        int col = (4 * wave + c) * 16 + m;
        float bkv = b_k[col];
#pragma unroll
        for (int r = 0; r < 4; ++r) {
          int rowl = rt * 16 + quad * 4 + r;
          int br = rowl / 19; int bs = br > 3 ? 3 : br;
          float kv = aK[rt][c][r] + bkv;
          kv = kv > 0.f ? kv : 0.f;
          part[r] += kv * qh[bs * 256 + col];
        }
      }
#pragma unroll
      for (int r = 0; r < 4; ++r) {
        float p = part[r];
        p += __shfl_xor(p, 1, 64);
        p += __shfl_xor(p, 2, 64);
        p += __shfl_xor(p, 4, 64);
        p += __shfl_xor(p, 8, 64);
        if (m == 0) spart[wave * 96 + rt * 16 + quad * 4 + r] = p;
      }
    }
  }
  __syncthreads();
  if (tid < 4) {
    float sc[19];
    float mx = -1e30f;
#pragma unroll
    for (int j = 0; j < 19; ++j) {
      int row = tid * 19 + j;
      float s = (spart[row] + spart[96 + row] + spart[192 + row] + spart[288 + row]) * 0.0625f;
      sc[j] = s; mx = fmaxf(mx, s);
    }
    float sum = 0.f;
#pragma unroll
    for (int j = 0; j < 19; ++j) { float e = __expf(sc[j] - mx); sc[j] = e; sum += e; }
    float inv = 1.f / sum;
#pragma unroll
    for (int j = 0; j < 19; ++j) {
      float a = sc[j] * inv;
      attl[tid * 19 + j] = a;
      att_out[(size_t)(b0 + tid) * 19 + j] = a;
    }
  }
  __syncthreads();

  // ---- pass V: v-accumulate (same structure), then h epilogue
  {
    f32x4 aV[5][4];
#pragma unroll
    for (int rt = 0; rt < 5; ++rt)
#pragma unroll
      for (int c = 0; c < 4; ++c) aV[rt][c] = z4;

    for (int ch = 0; ch < 8; ++ch) {
      const int kc = ch * 32;
      bf16x8 bV[4];
#pragma unroll
      for (int c = 0; c < 4; ++c)
        bV[c] = *(const bf16x8*)(WtVc + (size_t)ch * 8192 + ((4 * wave + c) * 16 + m) * 32 + quad * 8);
#pragma unroll
      for (int rt = 0; rt < 5; ++rt) {
        bf16x8 a = *(const bf16x8*)(ldsO + (rt * 16 + m) * 264 + kc + quad * 8);
#pragma unroll
        for (int c = 0; c < 4; ++c)
          aV[rt][c] = __builtin_amdgcn_mfma_f32_16x16x32_bf16(a, bV[c], aV[rt][c], 0, 0, 0);
      }
    }

    // epilogue: +sv, relu, *att, bucket into per-batch h, reduce
    float hacc[4][4];   // [c][batch]
#pragma unroll
    for (int c = 0; c < 4; ++c)
#pragma unroll
      for (int bb = 0; bb < 4; ++bb) hacc[c][bb] = 0.f;
#pragma unroll
    for (int rt = 0; rt < 5; ++rt)
#pragma unroll
      for (int c = 0; c < 4; ++c) {
        int col = (4 * wave + c) * 16 + m;
#pragma unroll
        for (int r = 0; r < 4; ++r) {
          int rowl = rt * 16 + quad * 4 + r;
          int br = rowl / 19; int bs = br > 3 ? 3 : br;
          float v = aV[rt][c][r] + svl[bs * 256 + col];
          v = v > 0.f ? v : 0.f;
          int ai = bs * 19 + (rowl - bs * 19);
          float hv = v * attl[ai < 96 ? ai : 95];
#pragma unroll
          for (int bb = 0; bb < 4; ++bb)
            hacc[c][bb] += (br == bb) ? hv : 0.f;
        }
      }
#pragma unroll
    for (int c = 0; c < 4; ++c)
#pragma unroll
      for (int bb = 0; bb < 4; ++bb) {
        float h = hacc[c][bb];
        h += __shfl_xor(h, 16, 64);
        h += __shfl_xor(h, 32, 64);
        if (quad == 0) qh[bb * 256 + (4 * wave + c) * 16 + m] = h;
      }
  }
  __syncthreads();
  for (int i = tid; i < 1024; i += 256)
    hb[(size_t)(b0 + (i >> 8)) * 256 + (i & 255)] = (bf16)qh[i];
}

// ---------------------------------------------------------------------------
extern "C" void kernel_launch(void* const* d_in, const int* in_sizes, int n_in,
                              void* d_out, int out_size, void* d_ws, size_t ws_size,
                              hipStream_t stream) {
  (void)in_sizes; (void)n_in; (void)out_size; (void)ws_size;
  const float* x      = (const float*)d_in[0];
  const float* eps    = (const float*)d_in[1];
  const float* W_mu   = (const float*)d_in[2];
  const float* b_mu   = (const float*)d_in[3];
  const float* W_var  = (const float*)d_in[4];
  const float* b_var  = (const float*)d_in[5];
  const float* W_self = (const float*)d_in[6];
  const float* b_self = (const float*)d_in[7];
  const float* W_other= (const float*)d_in[8];
  const float* b_other= (const float*)d_in[9];
  const float* W_q    = (const float*)d_in[10];
  const float* b_q    = (const float*)d_in[11];
  const float* W_k    = (const float*)d_in[12];
  const float* b_k    = (const float*)d_in[13];
  const float* W_v    = (const float*)d_in[14];
  const float* b_v    = (const float*)d_in[15];
  const float* W_a    = (const float*)d_in[16];
  const float* b_a    = (const float*)d_in[17];

  char* wsb = (char*)d_ws;
  bf16* WtMu    = (bf16*)(wsb + OFF_WT_MU);
  bf16* WtVar   = (bf16*)(wsb + OFF_WT_VAR);
  bf16* WtSelf  = (bf16*)(wsb + OFF_WT_SELF);
  bf16* WtOther = (bf16*)(wsb + OFF_WT_OTHER);
  bf16* WtQ     = (bf16*)(wsb + OFF_WT_Q);
  bf16* WtK     = (bf16*)(wsb + OFF_WT_K);
  bf16* WtV1    = (bf16*)(wsb + OFF_WT_V1);
  bf16* WtV2    = (bf16*)(wsb + OFF_WT_V2);
  bf16* WtA1    = (bf16*)(wsb + OFF_WT_A1);
  bf16* WtA2    = (bf16*)(wsb + OFF_WT_A2);
  bf16* zbuf    = (bf16*)(wsb + OFF_Z);
  bf16* selfbuf = (bf16*)(wsb + OFF_SELF);
  bf16* qbuf    = (bf16*)(wsb + OFF_Q);
  bf16* svbuf   = (bf16*)(wsb + OFF_SV);
  bf16* hbuf    = (bf16*)(wsb + OFF_H);

  float* out = (float*)d_out;
  float* att_out = out + (size_t)NB * 256;

  dim3 blk(256);
  wprep<<<dim3(160, 10), blk, 0, stream>>>(W_mu, W_var, W_self, W_other, W_q, W_k, W_v, W_a, wsb);
  // z = eps*exp(0.5*logvar)+mu  (fused mu/var GEMM, K=576)
  gemm_k<0, true><<<NB / 64, blk, 0, stream>>>(x, nullptr, 568, 576, 568,
                                               WtMu, WtVar, b_mu, b_var, eps, zbuf);
  // self_em = relu(x[:, :36] @ W_self + b_self)  (K=64, zero-padded weights)
  gemm_k<1, true><<<NB / 64, blk, 0, stream>>>(x, nullptr, 568, 64, 568,
                                               WtSelf, nullptr, b_self, nullptr, nullptr, selfbuf);
  // q = relu(z @ W_q + b_q)
  gemm_k<1, false><<<NB / 64, blk, 0, stream>>>(zbuf, nullptr, 256, 256, 256,
                                                WtQ, nullptr, b_q, nullptr, nullptr, qbuf);
  // sv = self_em @ W_v[256:] + b_v   (no relu)
  gemm_k<2, false><<<NB / 64, blk, 0, stream>>>(selfbuf, nullptr, 256, 256, 256,
                                                WtV2, nullptr, b_v, nullptr, nullptr, svbuf);
  // fused: other_em -> k -> scores -> softmax -> v -> h
  k_fused<<<NB / 4, blk, 0, stream>>>(x, qbuf, svbuf, WtOther, b_other, WtK, b_k,
                                      WtV1, att_out, hbuf);
  // out = relu([h; self_em] @ W_a + b_a)
  gemm_k<3, false><<<NB / 64, blk, 0, stream>>>(hbuf, selfbuf, 256, 256, 256,
                                                WtA1, WtA2, b_a, nullptr, nullptr, out);
}

// Round 7
// 379.506 us; speedup vs baseline: 2.9391x; 1.0346x over previous
//
#include <hip/hip_runtime.h>

typedef __bf16 bf16;
typedef __bf16 bf16x4 __attribute__((ext_vector_type(4)));
typedef __bf16 bf16x8 __attribute__((ext_vector_type(8)));
typedef float  f32x4  __attribute__((ext_vector_type(4)));

// Problem constants
#define NB    16384      // batch
#define NOBS  568
#define NH    256
#define NAG   19         // N_OTHER

// ws byte offsets (all 16B aligned)
#define OFF_WT_MU    0u          // [256][576] bf16 (flat [n][kpad])
#define OFF_WT_VAR   294912u     // [256][576]
#define OFF_WT_SELF  589824u     // [256][64]
#define OFF_WT_OTHER 622592u     // [256][32]  (chunk-major == flat at K=32)
#define OFF_WT_Q     638976u     // [256][256] flat
#define OFF_WT_K     770048u     // CHUNK-MAJOR [8][256][32]
#define OFF_WT_V1    901120u     // CHUNK-MAJOR [8][256][32]
#define OFF_WT_V2    1032192u    // flat
#define OFF_WT_A1    1163264u    // flat
#define OFF_WT_A2    1294336u    // flat
#define OFF_Z        1425408u    // [16384][256] bf16
#define OFF_SELF     9814016u
#define OFF_Q        18202624u
#define OFF_SV       26591232u   // bf16 (includes b_v)
#define OFF_H        34979840u

static __device__ __forceinline__ unsigned short bfbits(float v) {
  bf16 b = (bf16)v;
  union { bf16 b; unsigned short u; } cvt; cvt.b = b; return cvt.u;
}

// ---------------------------------------------------------------------------
// Weight prep: fp32 W[k][n] -> bf16. Flat: Wt[n][kpad] (zero-padded K).
// Chunked (for k_fused streaming): Wt[k/32][n][k%32] so a wave's B-frag
// loads are contiguous 64B runs.  (exact round-5 version)
// ---------------------------------------------------------------------------
__global__ __launch_bounds__(256) void wprep(
    const float* __restrict__ Wmu, const float* __restrict__ Wvar,
    const float* __restrict__ Wself, const float* __restrict__ Wother,
    const float* __restrict__ Wq, const float* __restrict__ Wk,
    const float* __restrict__ Wv, const float* __restrict__ Wa, char* wsb)
{
  const float* src; bf16* dst; int K, Kp; bool chunked = false;
  switch (blockIdx.y) {
    case 0: src = Wmu;        dst = (bf16*)(wsb + OFF_WT_MU);    K = 568; Kp = 576; break;
    case 1: src = Wvar;       dst = (bf16*)(wsb + OFF_WT_VAR);   K = 568; Kp = 576; break;
    case 2: src = Wself;      dst = (bf16*)(wsb + OFF_WT_SELF);  K = 36;  Kp = 64;  break;
    case 3: src = Wother;     dst = (bf16*)(wsb + OFF_WT_OTHER); K = 28;  Kp = 32;  break;
    case 4: src = Wq;         dst = (bf16*)(wsb + OFF_WT_Q);     K = 256; Kp = 256; break;
    case 5: src = Wk;         dst = (bf16*)(wsb + OFF_WT_K);     K = 256; Kp = 256; chunked = true; break;
    case 6: src = Wv;         dst = (bf16*)(wsb + OFF_WT_V1);    K = 256; Kp = 256; chunked = true; break;
    case 7: src = Wv + 65536; dst = (bf16*)(wsb + OFF_WT_V2);    K = 256; Kp = 256; break;
    case 8: src = Wa;         dst = (bf16*)(wsb + OFF_WT_A1);    K = 256; Kp = 256; break;
    default: src = Wa + 65536; dst = (bf16*)(wsb + OFF_WT_A2);   K = 256; Kp = 256; break;
  }
  int total = 256 * Kp;
  if (chunked) {
    for (int i = blockIdx.x * 256 + threadIdx.x; i < total; i += gridDim.x * 256) {
      int ch = i >> 13, n = (i >> 5) & 255, kk = i & 31;
      int k = ch * 32 + kk;
      dst[i] = (bf16)src[k * 256 + n];
    }
  } else {
    for (int i = blockIdx.x * 256 + threadIdx.x; i < total; i += gridDim.x * 256) {
      int n = i / Kp, k = i - n * Kp;
      dst[i] = (k < K) ? (bf16)src[k * 256 + n] : (bf16)0.f;
    }
  }
}

// ---------------------------------------------------------------------------
// Generic GEMM, BK=32.  ROUND-7 CHANGE (only change vs round-5): each block
// now owns 64 rows x 128 cols (blockIdx.y = col half) -> grid 512 = 2
// blocks/CU instead of 1 (round-5 gemm ran at 1 block/CU: zero TLP, every
// barrier drain exposed).  LDS 25.6 KB, acc[8] = 32 VGPR/wave.
// Wave w owns rows [w*16,w*16+16) x the block's 128 cols.
// EMODE: 0 = Z (dual Wt: mu & logvar -> z bf16), 1 = relu->bf16,
//        2 = +bias->bf16 (no relu), 3 = dual-A relu->f32 (final out)
// ---------------------------------------------------------------------------
template<int EMODE, bool AF32>
__global__ __launch_bounds__(256, 2) void gemm_k(
    const void* __restrict__ Aptr, const void* __restrict__ A2ptr,
    int lda, int K, int Klimit,
    const bf16* __restrict__ Wt, const bf16* __restrict__ Wt2,
    const float* __restrict__ bias, const float* __restrict__ bias2,
    const float* __restrict__ epsp, void* __restrict__ outp)
{
  constexpr bool DUALB = (EMODE == 0);
  constexpr bool DUALA = (EMODE == 3);
  __shared__ bf16 ldsA[64 * 40];
  __shared__ bf16 ldsB[128 * 40];
  __shared__ bf16 ldsB2[DUALB ? 128 * 40 : 8];

  const int tid = threadIdx.x;
  const int wave = tid >> 6;
  const int lane = tid & 63;
  const int quad = lane >> 4;
  const int m = lane & 15;
  const int rowbase = blockIdx.x * 64;
  const int colbase = blockIdx.y * 128;

  f32x4 acc[8];
  f32x4 accB[DUALB ? 8 : 1];
  const f32x4 z4 = {0.f, 0.f, 0.f, 0.f};
#pragma unroll
  for (int ct = 0; ct < 8; ++ct) acc[ct] = z4;
  if constexpr (DUALB) {
#pragma unroll
    for (int ct = 0; ct < 8; ++ct) accB[ct] = z4;
  }

  const int npass = DUALA ? 2 : 1;
  for (int pass = 0; pass < npass; ++pass) {
    const void* Ap = (pass == 0) ? Aptr : A2ptr;
    const bf16* Wp = (pass == 0) ? Wt : Wt2;
    for (int kc = 0; kc < K; kc += 32) {
      __syncthreads();
      if constexpr (AF32) {
        const float* Af = (const float*)Ap;
#pragma unroll
        for (int it = 0; it < 2; ++it) {
          int p = tid + 256 * it;          // 512 float4 segments (64 rows x 8)
          int r = p >> 3, fs = p & 7;
          int k = kc + fs * 4;
          const float* src = Af + (size_t)(rowbase + r) * lda + k;
          float v0, v1, v2, v3;
          if (k + 4 <= Klimit) {
            float4 v = *(const float4*)src;
            v0 = v.x; v1 = v.y; v2 = v.z; v3 = v.w;
          } else {
            v0 = (k + 0 < Klimit) ? src[0] : 0.f;
            v1 = (k + 1 < Klimit) ? src[1] : 0.f;
            v2 = (k + 2 < Klimit) ? src[2] : 0.f;
            v3 = (k + 3 < Klimit) ? src[3] : 0.f;
          }
          bf16x4 o = {(bf16)v0, (bf16)v1, (bf16)v2, (bf16)v3};
          *(bf16x4*)(ldsA + r * 40 + fs * 4) = o;
        }
      } else {
        const bf16* Ab = (const bf16*)Ap;
        {
          int p = tid;                      // 256 bf16x8 segments (64 rows x 4)
          int r = p >> 2, f = p & 3;
          *(bf16x8*)(ldsA + r * 40 + f * 8) =
              *(const bf16x8*)(Ab + (size_t)(rowbase + r) * lda + kc + f * 8);
        }
      }
#pragma unroll
      for (int it = 0; it < 2; ++it) {
        int p = tid + 256 * it;             // 512 bf16x8 segments (128 rows x 4)
        int n = p >> 2, f = p & 3;
        *(bf16x8*)(ldsB + n * 40 + f * 8) =
            *(const bf16x8*)(Wt + (size_t)(colbase + n) * K + kc + f * 8);
      }
      if constexpr (DUALB) {
#pragma unroll
        for (int it = 0; it < 2; ++it) {
          int p = tid + 256 * it;
          int n = p >> 2, f = p & 3;
          *(bf16x8*)(ldsB2 + n * 40 + f * 8) =
              *(const bf16x8*)(Wt2 + (size_t)(colbase + n) * K + kc + f * 8);
        }
      }
      // (non-dual passes use Wp == Wt for pass 0; DUALA pass 1 streams Wt2)
      if constexpr (DUALA) {
        if (pass == 1) {
          // overwrite ldsB with Wt2 tile (A2 pass) -- done above reads Wt;
          // redo with Wp to keep single code path correct
        }
      }
      __syncthreads();
      bf16x8 afrag = *(const bf16x8*)(ldsA + (wave * 16 + m) * 40 + quad * 8);
#pragma unroll
      for (int ct = 0; ct < 8; ++ct) {
        bf16x8 bfrag = *(const bf16x8*)(ldsB + (ct * 16 + m) * 40 + quad * 8);
        acc[ct] = __builtin_amdgcn_mfma_f32_16x16x32_bf16(afrag, bfrag, acc[ct], 0, 0, 0);
        if constexpr (DUALB) {
          bf16x8 b2 = *(const bf16x8*)(ldsB2 + (ct * 16 + m) * 40 + quad * 8);
          accB[ct] = __builtin_amdgcn_mfma_f32_16x16x32_bf16(afrag, b2, accB[ct], 0, 0, 0);
        }
      }
      (void)Wp;
    }
  }
#pragma unroll
  for (int ct = 0; ct < 8; ++ct) {
    const int col = colbase + ct * 16 + m;
    const float bv = bias[col];
#pragma unroll
    for (int r = 0; r < 4; ++r) {
      const size_t row = (size_t)rowbase + wave * 16 + quad * 4 + r;
      float v = acc[ct][r] + bv;
      if constexpr (EMODE == 0) {
        float lv = accB[ct][r] + bias2[col];
        float zz = epsp[row * 256 + col] * __expf(0.5f * lv) + v;
        ((bf16*)outp)[row * 256 + col] = (bf16)zz;
      } else if constexpr (EMODE == 1) {
        ((bf16*)outp)[row * 256 + col] = (bf16)(v > 0.f ? v : 0.f);
      } else if constexpr (EMODE == 2) {
        ((bf16*)outp)[row * 256 + col] = (bf16)v;
      } else {
        ((float*)outp)[row * 256 + col] = (v > 0.f ? v : 0.f);
      }
    }
  }
}

// DUALA needs the B-tile to come from Wt (pass 0) or Wt2 (pass 1).  The
// template above streams Wt only; specialize the dual-A case by calling it
// twice would change semantics (acc must accumulate across passes), so for
// EMODE==3 we pass Wt2 through the staging via this wrapper trick: the
// staging loop must read Wp.  To keep the round-5-verified structure intact,
// EMODE==3 uses a dedicated kernel below.
template<bool UNUSED>
__global__ __launch_bounds__(256, 2) void gemm_dualA(
    const bf16* __restrict__ A1, const bf16* __restrict__ A2,
    const bf16* __restrict__ Wt1, const bf16* __restrict__ Wt2,
    const float* __restrict__ bias, float* __restrict__ outp)
{
  __shared__ bf16 ldsA[64 * 40];
  __shared__ bf16 ldsB[128 * 40];

  const int tid = threadIdx.x;
  const int wave = tid >> 6;
  const int lane = tid & 63;
  const int quad = lane >> 4;
  const int m = lane & 15;
  const int rowbase = blockIdx.x * 64;
  const int colbase = blockIdx.y * 128;

  f32x4 acc[8];
  const f32x4 z4 = {0.f, 0.f, 0.f, 0.f};
#pragma unroll
  for (int ct = 0; ct < 8; ++ct) acc[ct] = z4;

  for (int pass = 0; pass < 2; ++pass) {
    const bf16* Ap = (pass == 0) ? A1 : A2;
    const bf16* Wp = (pass == 0) ? Wt1 : Wt2;
    for (int kc = 0; kc < 256; kc += 32) {
      __syncthreads();
      {
        int p = tid;
        int r = p >> 2, f = p & 3;
        *(bf16x8*)(ldsA + r * 40 + f * 8) =
            *(const bf16x8*)(Ap + (size_t)(rowbase + r) * 256 + kc + f * 8);
      }
#pragma unroll
      for (int it = 0; it < 2; ++it) {
        int p = tid + 256 * it;
        int n = p >> 2, f = p & 3;
        *(bf16x8*)(ldsB + n * 40 + f * 8) =
            *(const bf16x8*)(Wp + (size_t)(colbase + n) * 256 + kc + f * 8);
      }
      __syncthreads();
      bf16x8 afrag = *(const bf16x8*)(ldsA + (wave * 16 + m) * 40 + quad * 8);
#pragma unroll
      for (int ct = 0; ct < 8; ++ct) {
        bf16x8 bfrag = *(const bf16x8*)(ldsB + (ct * 16 + m) * 40 + quad * 8);
        acc[ct] = __builtin_amdgcn_mfma_f32_16x16x32_bf16(afrag, bfrag, acc[ct], 0, 0, 0);
      }
    }
  }
#pragma unroll
  for (int ct = 0; ct < 8; ++ct) {
    const int col = colbase + ct * 16 + m;
    const float bv = bias[col];
#pragma unroll
    for (int r = 0; r < 4; ++r) {
      const size_t row = (size_t)rowbase + wave * 16 + quad * 4 + r;
      float v = acc[ct][r] + bv;
      outp[row * 256 + col] = (v > 0.f ? v : 0.f);
    }
  }
}

// ---------------------------------------------------------------------------
// Fused attention (EXACT round-5 version -- known passing).
// ---------------------------------------------------------------------------
__global__ __launch_bounds__(256, 2) void k_fused(
    const float* __restrict__ x, const bf16* __restrict__ qb,
    const bf16* __restrict__ svb,
    const bf16* __restrict__ WtOther, const float* __restrict__ b_other,
    const bf16* __restrict__ WtKc, const float* __restrict__ b_k,
    const bf16* __restrict__ WtVc,
    float* __restrict__ att_out, bf16* __restrict__ hb)
{
  __shared__ bf16 ldsO[80 * 264];     // other_em (16B-group stride 33)
  __shared__ bf16 ldsA1[80 * 40];     // agents_info tile
  __shared__ float qh[1024];          // q, later h partials
  __shared__ float svl[1024];         // sv (self-half of v, incl. b_v)
  __shared__ float spart[4 * 96];     // per-wave score partials
  __shared__ float attl[96];          // att weights per row

  const int tid = threadIdx.x, wave = tid >> 6, lane = tid & 63;
  const int quad = lane >> 4, m = lane & 15;
  const int b0 = blockIdx.x * 4;

  // ---- phase 0: stage q, sv, agents_info
  for (int i = tid; i < 1024; i += 256) {
    qh[i]  = (float)qb[(size_t)b0 * 256 + i];
    svl[i] = (float)svb[(size_t)b0 * 256 + i];
  }
  for (int i = tid; i < 80 * 16; i += 256) {
    int r = i >> 4, kk = (i & 15) * 2;
    float v0 = 0.f, v1 = 0.f;
    if (r < 76) {
      int bb = b0 + r / 19, n = r % 19;
      const float* base = x + (size_t)bb * NOBS + 36 + n * 28;
      if (kk < 28) v0 = base[kk];
      if (kk + 1 < 28) v1 = base[kk + 1];
    }
    unsigned u0 = bfbits(v0), u1 = bfbits(v1);
    *(unsigned*)(ldsA1 + r * 40 + kk) = u0 | (u1 << 16);
  }
  __syncthreads();

  const f32x4 z4 = {0.f, 0.f, 0.f, 0.f};

  // ---- phase 1: other_em = relu(A1 @ WtOther^T + b_other), K=32
  {
    f32x4 acc1[5][4];
    bf16x8 bfr[4];
#pragma unroll
    for (int c = 0; c < 4; ++c)
      bfr[c] = *(const bf16x8*)(WtOther + ((4 * wave + c) * 16 + m) * 32 + quad * 8);
#pragma unroll
    for (int rt = 0; rt < 5; ++rt) {
      bf16x8 a = *(const bf16x8*)(ldsA1 + (rt * 16 + m) * 40 + quad * 8);
#pragma unroll
      for (int c = 0; c < 4; ++c)
        acc1[rt][c] = __builtin_amdgcn_mfma_f32_16x16x32_bf16(a, bfr[c], z4, 0, 0, 0);
    }
#pragma unroll
    for (int rt = 0; rt < 5; ++rt)
#pragma unroll
      for (int c = 0; c < 4; ++c) {
        int col = (4 * wave + c) * 16 + m;
        float bv = b_other[col];
#pragma unroll
        for (int r = 0; r < 4; ++r) {
          float v = acc1[rt][c][r] + bv;
          v = v > 0.f ? v : 0.f;
          unsigned u = bfbits(v);
          unsigned other = (unsigned)__shfl_xor((int)u, 1, 64);
          if ((m & 1) == 0) {
            int rowl = rt * 16 + quad * 4 + r;
            *(unsigned*)(ldsO + rowl * 264 + col) = u | (other << 16);
          }
        }
      }
  }
  __syncthreads();

  // ---- pass K: k-accumulate, barrier-free (B direct from global)
  {
    f32x4 aK[5][4];
#pragma unroll
    for (int rt = 0; rt < 5; ++rt)
#pragma unroll
      for (int c = 0; c < 4; ++c) aK[rt][c] = z4;

    for (int ch = 0; ch < 8; ++ch) {
      const int kc = ch * 32;
      bf16x8 bK[4];
#pragma unroll
      for (int c = 0; c < 4; ++c)
        bK[c] = *(const bf16x8*)(WtKc + (size_t)ch * 8192 + ((4 * wave + c) * 16 + m) * 32 + quad * 8);
#pragma unroll
      for (int rt = 0; rt < 5; ++rt) {
        bf16x8 a = *(const bf16x8*)(ldsO + (rt * 16 + m) * 264 + kc + quad * 8);
#pragma unroll
        for (int c = 0; c < 4; ++c)
          aK[rt][c] = __builtin_amdgcn_mfma_f32_16x16x32_bf16(a, bK[c], aK[rt][c], 0, 0, 0);
      }
    }

    // scores: relu(k)+b_k dot q, reduce across lanes then waves
#pragma unroll
    for (int rt = 0; rt < 5; ++rt) {
      float part[4] = {0.f, 0.f, 0.f, 0.f};
#pragma unroll
      for (int c = 0; c < 4; ++c) {
        int col = (4 * wave + c) * 16 + m;
        float bkv = b_k[col];
#pragma unroll
        for (int r = 0; r < 4; ++r) {
          int rowl = rt * 16 + quad * 4 + r;
          int br = rowl / 19; int bs = br > 3 ? 3 : br;
          float kv = aK[rt][c][r] + bkv;
          kv = kv > 0.f ? kv : 0.f;
          part[r] += kv * qh[bs * 256 + col];
        }
      }
#pragma unroll
      for (int r = 0; r < 4; ++r) {
        float p = part[r];
        p += __shfl_xor(p, 1, 64);
        p += __shfl_xor(p, 2, 64);
        p += __shfl_xor(p, 4, 64);
        p += __shfl_xor(p, 8, 64);
        if (m == 0) spart[wave * 96 + rt * 16 + quad * 4 + r] = p;
      }
    }
  }
  __syncthreads();
  if (tid < 4) {
    float sc[19];
    float mx = -1e30f;
#pragma unroll
    for (int j = 0; j < 19; ++j) {
      int row = tid * 19 + j;
      float s = (spart[row] + spart[96 + row] + spart[192 + row] + spart[288 + row]) * 0.0625f;
      sc[j] = s; mx = fmaxf(mx, s);
    }
    float sum = 0.f;
#pragma unroll
    for (int j = 0; j < 19; ++j) { float e = __expf(sc[j] - mx); sc[j] = e; sum += e; }
    float inv = 1.f / sum;
#pragma unroll
    for (int j = 0; j < 19; ++j) {
      float a = sc[j] * inv;
      attl[tid * 19 + j] = a;
      att_out[(size_t)(b0 + tid) * 19 + j] = a;
    }
  }
  __syncthreads();

  // ---- pass V: v-accumulate (same structure), then h epilogue
  {
    f32x4 aV[5][4];
#pragma unroll
    for (int rt = 0; rt < 5; ++rt)
#pragma unroll
      for (int c = 0; c < 4; ++c) aV[rt][c] = z4;

    for (int ch = 0; ch < 8; ++ch) {
      const int kc = ch * 32;
      bf16x8 bV[4];
#pragma unroll
      for (int c = 0; c < 4; ++c)
        bV[c] = *(const bf16x8*)(WtVc + (size_t)ch * 8192 + ((4 * wave + c) * 16 + m) * 32 + quad * 8);
#pragma unroll
      for (int rt = 0; rt < 5; ++rt) {
        bf16x8 a = *(const bf16x8*)(ldsO + (rt * 16 + m) * 264 + kc + quad * 8);
#pragma unroll
        for (int c = 0; c < 4; ++c)
          aV[rt][c] = __builtin_amdgcn_mfma_f32_16x16x32_bf16(a, bV[c], aV[rt][c], 0, 0, 0);
      }
    }

    // epilogue: +sv, relu, *att, bucket into per-batch h, reduce
    float hacc[4][4];   // [c][batch]
#pragma unroll
    for (int c = 0; c < 4; ++c)
#pragma unroll
      for (int bb = 0; bb < 4; ++bb) hacc[c][bb] = 0.f;
#pragma unroll
    for (int rt = 0; rt < 5; ++rt)
#pragma unroll
      for (int c = 0; c < 4; ++c) {
        int col = (4 * wave + c) * 16 + m;
#pragma unroll
        for (int r = 0; r < 4; ++r) {
          int rowl = rt * 16 + quad * 4 + r;
          int br = rowl / 19; int bs = br > 3 ? 3 : br;
          float v = aV[rt][c][r] + svl[bs * 256 + col];
          v = v > 0.f ? v : 0.f;
          int ai = bs * 19 + (rowl - bs * 19);
          float hv = v * attl[ai < 96 ? ai : 95];
#pragma unroll
          for (int bb = 0; bb < 4; ++bb)
            hacc[c][bb] += (br == bb) ? hv : 0.f;
        }
      }
#pragma unroll
    for (int c = 0; c < 4; ++c)
#pragma unroll
      for (int bb = 0; bb < 4; ++bb) {
        float h = hacc[c][bb];
        h += __shfl_xor(h, 16, 64);
        h += __shfl_xor(h, 32, 64);
        if (quad == 0) qh[bb * 256 + (4 * wave + c) * 16 + m] = h;
      }
  }
  __syncthreads();
  for (int i = tid; i < 1024; i += 256)
    hb[(size_t)(b0 + (i >> 8)) * 256 + (i & 255)] = (bf16)qh[i];
}

// ---------------------------------------------------------------------------
extern "C" void kernel_launch(void* const* d_in, const int* in_sizes, int n_in,
                              void* d_out, int out_size, void* d_ws, size_t ws_size,
                              hipStream_t stream) {
  (void)in_sizes; (void)n_in; (void)out_size; (void)ws_size;
  const float* x      = (const float*)d_in[0];
  const float* eps    = (const float*)d_in[1];
  const float* W_mu   = (const float*)d_in[2];
  const float* b_mu   = (const float*)d_in[3];
  const float* W_var  = (const float*)d_in[4];
  const float* b_var  = (const float*)d_in[5];
  const float* W_self = (const float*)d_in[6];
  const float* b_self = (const float*)d_in[7];
  const float* W_other= (const float*)d_in[8];
  const float* b_other= (const float*)d_in[9];
  const float* W_q    = (const float*)d_in[10];
  const float* b_q    = (const float*)d_in[11];
  const float* W_k    = (const float*)d_in[12];
  const float* b_k    = (const float*)d_in[13];
  const float* W_v    = (const float*)d_in[14];
  const float* b_v    = (const float*)d_in[15];
  const float* W_a    = (const float*)d_in[16];
  const float* b_a    = (const float*)d_in[17];

  char* wsb = (char*)d_ws;
  bf16* WtMu    = (bf16*)(wsb + OFF_WT_MU);
  bf16* WtVar   = (bf16*)(wsb + OFF_WT_VAR);
  bf16* WtSelf  = (bf16*)(wsb + OFF_WT_SELF);
  bf16* WtOther = (bf16*)(wsb + OFF_WT_OTHER);
  bf16* WtQ     = (bf16*)(wsb + OFF_WT_Q);
  bf16* WtK     = (bf16*)(wsb + OFF_WT_K);
  bf16* WtV1    = (bf16*)(wsb + OFF_WT_V1);
  bf16* WtV2    = (bf16*)(wsb + OFF_WT_V2);
  bf16* WtA1    = (bf16*)(wsb + OFF_WT_A1);
  bf16* WtA2    = (bf16*)(wsb + OFF_WT_A2);
  bf16* zbuf    = (bf16*)(wsb + OFF_Z);
  bf16* selfbuf = (bf16*)(wsb + OFF_SELF);
  bf16* qbuf    = (bf16*)(wsb + OFF_Q);
  bf16* svbuf   = (bf16*)(wsb + OFF_SV);
  bf16* hbuf    = (bf16*)(wsb + OFF_H);

  float* out = (float*)d_out;
  float* att_out = out + (size_t)NB * 256;

  dim3 blk(256);
  dim3 ggrid(NB / 64, 2);
  wprep<<<dim3(160, 10), blk, 0, stream>>>(W_mu, W_var, W_self, W_other, W_q, W_k, W_v, W_a, wsb);
  // z = eps*exp(0.5*logvar)+mu  (fused mu/var GEMM, K=576)
  gemm_k<0, true><<<ggrid, blk, 0, stream>>>(x, nullptr, 568, 576, 568,
                                             WtMu, WtVar, b_mu, b_var, eps, zbuf);
  // self_em = relu(x[:, :36] @ W_self + b_self)  (K=64, zero-padded weights)
  gemm_k<1, true><<<ggrid, blk, 0, stream>>>(x, nullptr, 568, 64, 568,
                                             WtSelf, nullptr, b_self, nullptr, nullptr, selfbuf);
  // q = relu(z @ W_q + b_q)
  gemm_k<1, false><<<ggrid, blk, 0, stream>>>(zbuf, nullptr, 256, 256, 256,
                                              WtQ, nullptr, b_q, nullptr, nullptr, qbuf);
  // sv = self_em @ W_v[256:] + b_v   (no relu)
  gemm_k<2, false><<<ggrid, blk, 0, stream>>>(selfbuf, nullptr, 256, 256, 256,
                                              WtV2, nullptr, b_v, nullptr, nullptr, svbuf);
  // fused: other_em -> k -> scores -> softmax -> v -> h
  k_fused<<<NB / 4, blk, 0, stream>>>(x, qbuf, svbuf, WtOther, b_other, WtK, b_k,
                                      WtV1, att_out, hbuf);
  // out = relu([h; self_em] @ W_a + b_a)   (dedicated dual-A kernel)
  gemm_dualA<true><<<ggrid, blk, 0, stream>>>(hbuf, selfbuf, WtA1, WtA2, b_a, out);
}

// Round 8
// 362.227 us; speedup vs baseline: 3.0793x; 1.0477x over previous
//
#include <hip/hip_runtime.h>

typedef __bf16 bf16;
typedef __bf16 bf16x4 __attribute__((ext_vector_type(4)));
typedef __bf16 bf16x8 __attribute__((ext_vector_type(8)));
typedef float  f32x4  __attribute__((ext_vector_type(4)));

// Problem constants
#define NB    16384      // batch
#define NOBS  568
#define NH    256
#define NAG   19         // N_OTHER

// ws byte offsets (all 16B aligned)
#define OFF_WT_MU    0u          // [256][576] bf16 (flat [n][kpad])
#define OFF_WT_VAR   294912u     // [256][576]
#define OFF_WT_SELF  589824u     // [256][64]
#define OFF_WT_OTHER 622592u     // [256][32]  (chunk-major == flat at K=32)
#define OFF_WT_Q     638976u     // [256][256] flat
#define OFF_WT_K     770048u     // CHUNK-MAJOR [8][256][32]
#define OFF_WT_V1    901120u     // CHUNK-MAJOR [8][256][32]
#define OFF_WT_V2    1032192u    // flat
#define OFF_WT_A1    1163264u    // flat
#define OFF_WT_A2    1294336u    // flat
#define OFF_Z        1425408u    // [16384][256] bf16
#define OFF_SELF     9814016u
#define OFF_Q        18202624u
#define OFF_SV       26591232u   // bf16 (includes b_v)
#define OFF_H        34979840u

static __device__ __forceinline__ unsigned short bfbits(float v) {
  bf16 b = (bf16)v;
  union { bf16 b; unsigned short u; } cvt; cvt.b = b; return cvt.u;
}

// ---------------------------------------------------------------------------
// Weight prep: fp32 W[k][n] -> bf16. Flat: Wt[n][kpad] (zero-padded K).
// Chunked (for k_fused streaming): Wt[k/32][n][k%32] so a wave's B-frag
// loads are contiguous 64B runs.  (exact round-5/7 version)
// ---------------------------------------------------------------------------
__global__ __launch_bounds__(256) void wprep(
    const float* __restrict__ Wmu, const float* __restrict__ Wvar,
    const float* __restrict__ Wself, const float* __restrict__ Wother,
    const float* __restrict__ Wq, const float* __restrict__ Wk,
    const float* __restrict__ Wv, const float* __restrict__ Wa, char* wsb)
{
  const float* src; bf16* dst; int K, Kp; bool chunked = false;
  switch (blockIdx.y) {
    case 0: src = Wmu;        dst = (bf16*)(wsb + OFF_WT_MU);    K = 568; Kp = 576; break;
    case 1: src = Wvar;       dst = (bf16*)(wsb + OFF_WT_VAR);   K = 568; Kp = 576; break;
    case 2: src = Wself;      dst = (bf16*)(wsb + OFF_WT_SELF);  K = 36;  Kp = 64;  break;
    case 3: src = Wother;     dst = (bf16*)(wsb + OFF_WT_OTHER); K = 28;  Kp = 32;  break;
    case 4: src = Wq;         dst = (bf16*)(wsb + OFF_WT_Q);     K = 256; Kp = 256; break;
    case 5: src = Wk;         dst = (bf16*)(wsb + OFF_WT_K);     K = 256; Kp = 256; chunked = true; break;
    case 6: src = Wv;         dst = (bf16*)(wsb + OFF_WT_V1);    K = 256; Kp = 256; chunked = true; break;
    case 7: src = Wv + 65536; dst = (bf16*)(wsb + OFF_WT_V2);    K = 256; Kp = 256; break;
    case 8: src = Wa;         dst = (bf16*)(wsb + OFF_WT_A1);    K = 256; Kp = 256; break;
    default: src = Wa + 65536; dst = (bf16*)(wsb + OFF_WT_A2);   K = 256; Kp = 256; break;
  }
  int total = 256 * Kp;
  if (chunked) {
    for (int i = blockIdx.x * 256 + threadIdx.x; i < total; i += gridDim.x * 256) {
      int ch = i >> 13, n = (i >> 5) & 255, kk = i & 31;
      int k = ch * 32 + kk;
      dst[i] = (bf16)src[k * 256 + n];
    }
  } else {
    for (int i = blockIdx.x * 256 + threadIdx.x; i < total; i += gridDim.x * 256) {
      int n = i / Kp, k = i - n * Kp;
      dst[i] = (k < K) ? (bf16)src[k * 256 + n] : (bf16)0.f;
    }
  }
}

// ---------------------------------------------------------------------------
// Generic GEMM, BK=32, 64 rows x 128 cols per block (exact round-7 version).
// ---------------------------------------------------------------------------
template<int EMODE, bool AF32>
__global__ __launch_bounds__(256, 2) void gemm_k(
    const void* __restrict__ Aptr, const void* __restrict__ A2ptr,
    int lda, int K, int Klimit,
    const bf16* __restrict__ Wt, const bf16* __restrict__ Wt2,
    const float* __restrict__ bias, const float* __restrict__ bias2,
    const float* __restrict__ epsp, void* __restrict__ outp)
{
  constexpr bool DUALB = (EMODE == 0);
  constexpr bool DUALA = (EMODE == 3);
  __shared__ bf16 ldsA[64 * 40];
  __shared__ bf16 ldsB[128 * 40];
  __shared__ bf16 ldsB2[DUALB ? 128 * 40 : 8];

  const int tid = threadIdx.x;
  const int wave = tid >> 6;
  const int lane = tid & 63;
  const int quad = lane >> 4;
  const int m = lane & 15;
  const int rowbase = blockIdx.x * 64;
  const int colbase = blockIdx.y * 128;

  f32x4 acc[8];
  f32x4 accB[DUALB ? 8 : 1];
  const f32x4 z4 = {0.f, 0.f, 0.f, 0.f};
#pragma unroll
  for (int ct = 0; ct < 8; ++ct) acc[ct] = z4;
  if constexpr (DUALB) {
#pragma unroll
    for (int ct = 0; ct < 8; ++ct) accB[ct] = z4;
  }

  const int npass = DUALA ? 2 : 1;
  for (int pass = 0; pass < npass; ++pass) {
    const void* Ap = (pass == 0) ? Aptr : A2ptr;
    const bf16* Wp = (pass == 0) ? Wt : Wt2;
    for (int kc = 0; kc < K; kc += 32) {
      __syncthreads();
      if constexpr (AF32) {
        const float* Af = (const float*)Ap;
#pragma unroll
        for (int it = 0; it < 2; ++it) {
          int p = tid + 256 * it;          // 512 float4 segments (64 rows x 8)
          int r = p >> 3, fs = p & 7;
          int k = kc + fs * 4;
          const float* src = Af + (size_t)(rowbase + r) * lda + k;
          float v0, v1, v2, v3;
          if (k + 4 <= Klimit) {
            float4 v = *(const float4*)src;
            v0 = v.x; v1 = v.y; v2 = v.z; v3 = v.w;
          } else {
            v0 = (k + 0 < Klimit) ? src[0] : 0.f;
            v1 = (k + 1 < Klimit) ? src[1] : 0.f;
            v2 = (k + 2 < Klimit) ? src[2] : 0.f;
            v3 = (k + 3 < Klimit) ? src[3] : 0.f;
          }
          bf16x4 o = {(bf16)v0, (bf16)v1, (bf16)v2, (bf16)v3};
          *(bf16x4*)(ldsA + r * 40 + fs * 4) = o;
        }
      } else {
        const bf16* Ab = (const bf16*)Ap;
        {
          int p = tid;                      // 256 bf16x8 segments (64 rows x 4)
          int r = p >> 2, f = p & 3;
          *(bf16x8*)(ldsA + r * 40 + f * 8) =
              *(const bf16x8*)(Ab + (size_t)(rowbase + r) * lda + kc + f * 8);
        }
      }
#pragma unroll
      for (int it = 0; it < 2; ++it) {
        int p = tid + 256 * it;             // 512 bf16x8 segments (128 rows x 4)
        int n = p >> 2, f = p & 3;
        *(bf16x8*)(ldsB + n * 40 + f * 8) =
            *(const bf16x8*)(Wt + (size_t)(colbase + n) * K + kc + f * 8);
      }
      if constexpr (DUALB) {
#pragma unroll
        for (int it = 0; it < 2; ++it) {
          int p = tid + 256 * it;
          int n = p >> 2, f = p & 3;
          *(bf16x8*)(ldsB2 + n * 40 + f * 8) =
              *(const bf16x8*)(Wt2 + (size_t)(colbase + n) * K + kc + f * 8);
        }
      }
      __syncthreads();
      bf16x8 afrag = *(const bf16x8*)(ldsA + (wave * 16 + m) * 40 + quad * 8);
#pragma unroll
      for (int ct = 0; ct < 8; ++ct) {
        bf16x8 bfrag = *(const bf16x8*)(ldsB + (ct * 16 + m) * 40 + quad * 8);
        acc[ct] = __builtin_amdgcn_mfma_f32_16x16x32_bf16(afrag, bfrag, acc[ct], 0, 0, 0);
        if constexpr (DUALB) {
          bf16x8 b2 = *(const bf16x8*)(ldsB2 + (ct * 16 + m) * 40 + quad * 8);
          accB[ct] = __builtin_amdgcn_mfma_f32_16x16x32_bf16(afrag, b2, accB[ct], 0, 0, 0);
        }
      }
      (void)Wp;
    }
  }
#pragma unroll
  for (int ct = 0; ct < 8; ++ct) {
    const int col = colbase + ct * 16 + m;
    const float bv = bias[col];
#pragma unroll
    for (int r = 0; r < 4; ++r) {
      const size_t row = (size_t)rowbase + wave * 16 + quad * 4 + r;
      float v = acc[ct][r] + bv;
      if constexpr (EMODE == 0) {
        float lv = accB[ct][r] + bias2[col];
        float zz = epsp[row * 256 + col] * __expf(0.5f * lv) + v;
        ((bf16*)outp)[row * 256 + col] = (bf16)zz;
      } else if constexpr (EMODE == 1) {
        ((bf16*)outp)[row * 256 + col] = (bf16)(v > 0.f ? v : 0.f);
      } else if constexpr (EMODE == 2) {
        ((bf16*)outp)[row * 256 + col] = (bf16)v;
      } else {
        ((float*)outp)[row * 256 + col] = (v > 0.f ? v : 0.f);
      }
    }
  }
}

// Dedicated dual-A GEMM for out = relu([h; self_em] @ W_a + b_a)
// (exact round-7 version)
template<bool UNUSED>
__global__ __launch_bounds__(256, 2) void gemm_dualA(
    const bf16* __restrict__ A1, const bf16* __restrict__ A2,
    const bf16* __restrict__ Wt1, const bf16* __restrict__ Wt2,
    const float* __restrict__ bias, float* __restrict__ outp)
{
  __shared__ bf16 ldsA[64 * 40];
  __shared__ bf16 ldsB[128 * 40];

  const int tid = threadIdx.x;
  const int wave = tid >> 6;
  const int lane = tid & 63;
  const int quad = lane >> 4;
  const int m = lane & 15;
  const int rowbase = blockIdx.x * 64;
  const int colbase = blockIdx.y * 128;

  f32x4 acc[8];
  const f32x4 z4 = {0.f, 0.f, 0.f, 0.f};
#pragma unroll
  for (int ct = 0; ct < 8; ++ct) acc[ct] = z4;

  for (int pass = 0; pass < 2; ++pass) {
    const bf16* Ap = (pass == 0) ? A1 : A2;
    const bf16* Wp = (pass == 0) ? Wt1 : Wt2;
    for (int kc = 0; kc < 256; kc += 32) {
      __syncthreads();
      {
        int p = tid;
        int r = p >> 2, f = p & 3;
        *(bf16x8*)(ldsA + r * 40 + f * 8) =
            *(const bf16x8*)(Ap + (size_t)(rowbase + r) * 256 + kc + f * 8);
      }
#pragma unroll
      for (int it = 0; it < 2; ++it) {
        int p = tid + 256 * it;
        int n = p >> 2, f = p & 3;
        *(bf16x8*)(ldsB + n * 40 + f * 8) =
            *(const bf16x8*)(Wp + (size_t)(colbase + n) * 256 + kc + f * 8);
      }
      __syncthreads();
      bf16x8 afrag = *(const bf16x8*)(ldsA + (wave * 16 + m) * 40 + quad * 8);
#pragma unroll
      for (int ct = 0; ct < 8; ++ct) {
        bf16x8 bfrag = *(const bf16x8*)(ldsB + (ct * 16 + m) * 40 + quad * 8);
        acc[ct] = __builtin_amdgcn_mfma_f32_16x16x32_bf16(afrag, bfrag, acc[ct], 0, 0, 0);
      }
    }
  }
#pragma unroll
  for (int ct = 0; ct < 8; ++ct) {
    const int col = colbase + ct * 16 + m;
    const float bv = bias[col];
#pragma unroll
    for (int r = 0; r < 4; ++r) {
      const size_t row = (size_t)rowbase + wave * 16 + quad * 4 + r;
      float v = acc[ct][r] + bv;
      outp[row * 256 + col] = (v > 0.f ? v : 0.f);
    }
  }
}

// ---------------------------------------------------------------------------
// Fused attention -- round-7 structure with an LDS DIET (the ONLY change this
// round): q/sv staged as bf16 (lossless: they are bf16 in ws), spart/attl
// overlaid on the dead ldsA1 region (barrier-separated lifetimes), h partials
// reuse qh16 (dead after scores).  58880 -> 52736 B => 3 blocks/CU.
// ---------------------------------------------------------------------------
__global__ __launch_bounds__(256, 3) void k_fused(
    const float* __restrict__ x, const bf16* __restrict__ qb,
    const bf16* __restrict__ svb,
    const bf16* __restrict__ WtOther, const float* __restrict__ b_other,
    const bf16* __restrict__ WtKc, const float* __restrict__ b_k,
    const bf16* __restrict__ WtVc,
    float* __restrict__ att_out, bf16* __restrict__ hb)
{
  __shared__ bf16 ldsO[80 * 264];     // 42240 B  other_em (16B-group stride 33)
  __shared__ bf16 ldsA1[80 * 40];     //  6400 B  agents tile; REUSED: spart/attl
  __shared__ bf16 qh16[1024];         //  2048 B  q (bf16); REUSED: h partials
  __shared__ bf16 svl16[1024];        //  2048 B  sv (bf16)
  // overlays on ldsA1 (dead after phase 1; transitions barrier-separated):
  float* spart = (float*)ldsA1;        // [0..320)  floats: 4 waves x 80 rows
  float* attl  = (float*)ldsA1 + 320;  // [320..400) floats: att weights

  const int tid = threadIdx.x, wave = tid >> 6, lane = tid & 63;
  const int quad = lane >> 4, m = lane & 15;
  const int b0 = blockIdx.x * 4;

  // ---- phase 0: stage q, sv (bf16 copies), agents_info
  for (int i = tid; i < 512; i += 256) {
    ((unsigned*)qh16)[i]  = ((const unsigned*)(qb  + (size_t)b0 * 256))[i];
    ((unsigned*)svl16)[i] = ((const unsigned*)(svb + (size_t)b0 * 256))[i];
  }
  for (int i = tid; i < 80 * 16; i += 256) {
    int r = i >> 4, kk = (i & 15) * 2;
    float v0 = 0.f, v1 = 0.f;
    if (r < 76) {
      int bb = b0 + r / 19, n = r % 19;
      const float* base = x + (size_t)bb * NOBS + 36 + n * 28;
      if (kk < 28) v0 = base[kk];
      if (kk + 1 < 28) v1 = base[kk + 1];
    }
    unsigned u0 = bfbits(v0), u1 = bfbits(v1);
    *(unsigned*)(ldsA1 + r * 40 + kk) = u0 | (u1 << 16);
  }
  __syncthreads();

  const f32x4 z4 = {0.f, 0.f, 0.f, 0.f};

  // ---- phase 1: other_em = relu(A1 @ WtOther^T + b_other), K=32
  {
    f32x4 acc1[5][4];
    bf16x8 bfr[4];
#pragma unroll
    for (int c = 0; c < 4; ++c)
      bfr[c] = *(const bf16x8*)(WtOther + ((4 * wave + c) * 16 + m) * 32 + quad * 8);
#pragma unroll
    for (int rt = 0; rt < 5; ++rt) {
      bf16x8 a = *(const bf16x8*)(ldsA1 + (rt * 16 + m) * 40 + quad * 8);
#pragma unroll
      for (int c = 0; c < 4; ++c)
        acc1[rt][c] = __builtin_amdgcn_mfma_f32_16x16x32_bf16(a, bfr[c], z4, 0, 0, 0);
    }
#pragma unroll
    for (int rt = 0; rt < 5; ++rt)
#pragma unroll
      for (int c = 0; c < 4; ++c) {
        int col = (4 * wave + c) * 16 + m;
        float bv = b_other[col];
#pragma unroll
        for (int r = 0; r < 4; ++r) {
          float v = acc1[rt][c][r] + bv;
          v = v > 0.f ? v : 0.f;
          unsigned u = bfbits(v);
          unsigned other = (unsigned)__shfl_xor((int)u, 1, 64);
          if ((m & 1) == 0) {
            int rowl = rt * 16 + quad * 4 + r;
            *(unsigned*)(ldsO + rowl * 264 + col) = u | (other << 16);
          }
        }
      }
  }
  __syncthreads();   // ldsA1 (agents tile) dead from here; spart/attl overlay

  // ---- pass K: k-accumulate, barrier-free (B direct from global)
  {
    f32x4 aK[5][4];
#pragma unroll
    for (int rt = 0; rt < 5; ++rt)
#pragma unroll
      for (int c = 0; c < 4; ++c) aK[rt][c] = z4;

    for (int ch = 0; ch < 8; ++ch) {
      const int kc = ch * 32;
      bf16x8 bK[4];
#pragma unroll
      for (int c = 0; c < 4; ++c)
        bK[c] = *(const bf16x8*)(WtKc + (size_t)ch * 8192 + ((4 * wave + c) * 16 + m) * 32 + quad * 8);
#pragma unroll
      for (int rt = 0; rt < 5; ++rt) {
        bf16x8 a = *(const bf16x8*)(ldsO + (rt * 16 + m) * 264 + kc + quad * 8);
#pragma unroll
        for (int c = 0; c < 4; ++c)
          aK[rt][c] = __builtin_amdgcn_mfma_f32_16x16x32_bf16(a, bK[c], aK[rt][c], 0, 0, 0);
      }
    }

    // scores: relu(k)+b_k dot q, reduce across lanes then waves
#pragma unroll
    for (int rt = 0; rt < 5; ++rt) {
      float part[4] = {0.f, 0.f, 0.f, 0.f};
#pragma unroll
      for (int c = 0; c < 4; ++c) {
        int col = (4 * wave + c) * 16 + m;
        float bkv = b_k[col];
#pragma unroll
        for (int r = 0; r < 4; ++r) {
          int rowl = rt * 16 + quad * 4 + r;
          int br = rowl / 19; int bs = br > 3 ? 3 : br;
          float kv = aK[rt][c][r] + bkv;
          kv = kv > 0.f ? kv : 0.f;
          part[r] += kv * (float)qh16[bs * 256 + col];
        }
      }
#pragma unroll
      for (int r = 0; r < 4; ++r) {
        float p = part[r];
        p += __shfl_xor(p, 1, 64);
        p += __shfl_xor(p, 2, 64);
        p += __shfl_xor(p, 4, 64);
        p += __shfl_xor(p, 8, 64);
        if (m == 0) spart[wave * 80 + rt * 16 + quad * 4 + r] = p;
      }
    }
  }
  __syncthreads();
  if (tid < 4) {
    float sc[19];
    float mx = -1e30f;
#pragma unroll
    for (int j = 0; j < 19; ++j) {
      int row = tid * 19 + j;
      float s = (spart[row] + spart[80 + row] + spart[160 + row] + spart[240 + row]) * 0.0625f;
      sc[j] = s; mx = fmaxf(mx, s);
    }
    float sum = 0.f;
#pragma unroll
    for (int j = 0; j < 19; ++j) { float e = __expf(sc[j] - mx); sc[j] = e; sum += e; }
    float inv = 1.f / sum;
#pragma unroll
    for (int j = 0; j < 19; ++j) {
      float a = sc[j] * inv;
      attl[tid * 19 + j] = a;
      att_out[(size_t)(b0 + tid) * 19 + j] = a;
    }
  }
  __syncthreads();

  // ---- pass V: v-accumulate (same structure), then h epilogue
  {
    f32x4 aV[5][4];
#pragma unroll
    for (int rt = 0; rt < 5; ++rt)
#pragma unroll
      for (int c = 0; c < 4; ++c) aV[rt][c] = z4;

    for (int ch = 0; ch < 8; ++ch) {
      const int kc = ch * 32;
      bf16x8 bV[4];
#pragma unroll
      for (int c = 0; c < 4; ++c)
        bV[c] = *(const bf16x8*)(WtVc + (size_t)ch * 8192 + ((4 * wave + c) * 16 + m) * 32 + quad * 8);
#pragma unroll
      for (int rt = 0; rt < 5; ++rt) {
        bf16x8 a = *(const bf16x8*)(ldsO + (rt * 16 + m) * 264 + kc + quad * 8);
#pragma unroll
        for (int c = 0; c < 4; ++c)
          aV[rt][c] = __builtin_amdgcn_mfma_f32_16x16x32_bf16(a, bV[c], aV[rt][c], 0, 0, 0);
      }
    }

    // epilogue: +sv, relu, *att, bucket into per-batch h, reduce
    float hacc[4][4];   // [c][batch]
#pragma unroll
    for (int c = 0; c < 4; ++c)
#pragma unroll
      for (int bb = 0; bb < 4; ++bb) hacc[c][bb] = 0.f;
#pragma unroll
    for (int rt = 0; rt < 5; ++rt)
#pragma unroll
      for (int c = 0; c < 4; ++c) {
        int col = (4 * wave + c) * 16 + m;
#pragma unroll
        for (int r = 0; r < 4; ++r) {
          int rowl = rt * 16 + quad * 4 + r;
          int br = rowl / 19; int bs = br > 3 ? 3 : br;
          float v = aV[rt][c][r] + (float)svl16[bs * 256 + col];
          v = v > 0.f ? v : 0.f;
          int ai = bs * 19 + (rowl - bs * 19);   // valid rows: ai <= 75
          float hv = v * attl[ai < 76 ? ai : 75];
#pragma unroll
          for (int bb = 0; bb < 4; ++bb)
            hacc[c][bb] += (br == bb) ? hv : 0.f;
        }
      }
    __syncthreads();   // all qh16 (q) readers done before h-partial overwrite
#pragma unroll
    for (int c = 0; c < 4; ++c)
#pragma unroll
      for (int bb = 0; bb < 4; ++bb) {
        float h = hacc[c][bb];
        h += __shfl_xor(h, 16, 64);
        h += __shfl_xor(h, 32, 64);
        if (quad == 0) qh16[bb * 256 + (4 * wave + c) * 16 + m] = (bf16)h;
      }
  }
  __syncthreads();
  for (int i = tid; i < 512; i += 256)
    ((unsigned*)(hb + (size_t)b0 * 256))[i] = ((const unsigned*)qh16)[i];
}

// ---------------------------------------------------------------------------
extern "C" void kernel_launch(void* const* d_in, const int* in_sizes, int n_in,
                              void* d_out, int out_size, void* d_ws, size_t ws_size,
                              hipStream_t stream) {
  (void)in_sizes; (void)n_in; (void)out_size; (void)ws_size;
  const float* x      = (const float*)d_in[0];
  const float* eps    = (const float*)d_in[1];
  const float* W_mu   = (const float*)d_in[2];
  const float* b_mu   = (const float*)d_in[3];
  const float* W_var  = (const float*)d_in[4];
  const float* b_var  = (const float*)d_in[5];
  const float* W_self = (const float*)d_in[6];
  const float* b_self = (const float*)d_in[7];
  const float* W_other= (const float*)d_in[8];
  const float* b_other= (const float*)d_in[9];
  const float* W_q    = (const float*)d_in[10];
  const float* b_q    = (const float*)d_in[11];
  const float* W_k    = (const float*)d_in[12];
  const float* b_k    = (const float*)d_in[13];
  const float* W_v    = (const float*)d_in[14];
  const float* b_v    = (const float*)d_in[15];
  const float* W_a    = (const float*)d_in[16];
  const float* b_a    = (const float*)d_in[17];

  char* wsb = (char*)d_ws;
  bf16* WtMu    = (bf16*)(wsb + OFF_WT_MU);
  bf16* WtVar   = (bf16*)(wsb + OFF_WT_VAR);
  bf16* WtSelf  = (bf16*)(wsb + OFF_WT_SELF);
  bf16* WtOther = (bf16*)(wsb + OFF_WT_OTHER);
  bf16* WtQ     = (bf16*)(wsb + OFF_WT_Q);
  bf16* WtK     = (bf16*)(wsb + OFF_WT_K);
  bf16* WtV1    = (bf16*)(wsb + OFF_WT_V1);
  bf16* WtV2    = (bf16*)(wsb + OFF_WT_V2);
  bf16* WtA1    = (bf16*)(wsb + OFF_WT_A1);
  bf16* WtA2    = (bf16*)(wsb + OFF_WT_A2);
  bf16* zbuf    = (bf16*)(wsb + OFF_Z);
  bf16* selfbuf = (bf16*)(wsb + OFF_SELF);
  bf16* qbuf    = (bf16*)(wsb + OFF_Q);
  bf16* svbuf   = (bf16*)(wsb + OFF_SV);
  bf16* hbuf    = (bf16*)(wsb + OFF_H);

  float* out = (float*)d_out;
  float* att_out = out + (size_t)NB * 256;

  dim3 blk(256);
  dim3 ggrid(NB / 64, 2);
  wprep<<<dim3(160, 10), blk, 0, stream>>>(W_mu, W_var, W_self, W_other, W_q, W_k, W_v, W_a, wsb);
  // z = eps*exp(0.5*logvar)+mu  (fused mu/var GEMM, K=576)
  gemm_k<0, true><<<ggrid, blk, 0, stream>>>(x, nullptr, 568, 576, 568,
                                             WtMu, WtVar, b_mu, b_var, eps, zbuf);
  // self_em = relu(x[:, :36] @ W_self + b_self)  (K=64, zero-padded weights)
  gemm_k<1, true><<<ggrid, blk, 0, stream>>>(x, nullptr, 568, 64, 568,
                                             WtSelf, nullptr, b_self, nullptr, nullptr, selfbuf);
  // q = relu(z @ W_q + b_q)
  gemm_k<1, false><<<ggrid, blk, 0, stream>>>(zbuf, nullptr, 256, 256, 256,
                                              WtQ, nullptr, b_q, nullptr, nullptr, qbuf);
  // sv = self_em @ W_v[256:] + b_v   (no relu)
  gemm_k<2, false><<<ggrid, blk, 0, stream>>>(selfbuf, nullptr, 256, 256, 256,
                                              WtV2, nullptr, b_v, nullptr, nullptr, svbuf);
  // fused: other_em -> k -> scores -> softmax -> v -> h
  k_fused<<<NB / 4, blk, 0, stream>>>(x, qbuf, svbuf, WtOther, b_other, WtK, b_k,
                                      WtV1, att_out, hbuf);
  // out = relu([h; self_em] @ W_a + b_a)   (dedicated dual-A kernel)
  gemm_dualA<true><<<ggrid, blk, 0, stream>>>(hbuf, selfbuf, WtA1, WtA2, b_a, out);
}